// Round 2
// baseline (2364.546 us; speedup 1.0000x reference)
//
#include <hip/hip_runtime.h>
#include <cstdint>
#include <cstddef>

#define EPS 1e-5f
#define BB 4096
#define TT 64
#define DDIM 128
#define NBLK 2
#define TCH 8
#define NCHUNK (TT / TCH)
#define MROWS (BB * TT)

// ---------------- embed: h = x @ w_in + b_in ----------------
__global__ __launch_bounds__(256) void k_embed(const float* __restrict__ x,
                                               const float* __restrict__ w_in,
                                               const float* __restrict__ b_in,
                                               float* __restrict__ h) {
    int idx = blockIdx.x * 256 + threadIdx.x;
    int row = idx >> 7, d = idx & 127;
    const float* xr = x + (size_t)row * 3;
    h[idx] = xr[0] * w_in[d] + xr[1] * w_in[128 + d] + xr[2] * w_in[256 + d] + b_in[d];
}

// ---------------- per-row LN stats (mu, rstd) ----------------
__global__ __launch_bounds__(256) void k_stats(const float* __restrict__ h,
                                               float* __restrict__ mu,
                                               float* __restrict__ rs) {
    int row = blockIdx.x * 4 + (threadIdx.x >> 6);
    int l = threadIdx.x & 63;
    float2 v = *(const float2*)(h + (size_t)row * 128 + l * 2);
    float s = v.x + v.y, ss = v.x * v.x + v.y * v.y;
#pragma unroll
    for (int off = 1; off < 64; off <<= 1) {
        s += __shfl_xor(s, off);
        ss += __shfl_xor(ss, off);
    }
    if (l == 0) {
        float m_ = s * (1.f / 128.f);
        mu[row] = m_;
        rs[row] = rsqrtf(ss * (1.f / 128.f) - m_ * m_ + EPS);
    }
}

// ---------------- GEMM: C = [LN(A)] @ B (+bias) (+gelu | +=res) ----------------
// M-tile 128, N-tile 128, K=128 staged in 4 slices of 32. 8x8 micro per thread.
// CHUNKED: A row rc maps to h row (rc/TCH)*TT + t0 + (rc%TCH) (gate-GEMM chunking).
// EPI: 0 = store, 1 = gelu+store, 2 = C += acc
template <bool DO_LN, bool CHUNKED, int EPI>
__global__ __launch_bounds__(256, 2) void k_gemm(
    const float* __restrict__ A, const float* __restrict__ Bw,
    const float* __restrict__ mu, const float* __restrict__ rs,
    const float* __restrict__ lng, const float* __restrict__ lnb,
    const float* __restrict__ bias, float* __restrict__ C,
    int ldb, int ldc, int t0) {
    __shared__ float As[32][132];  // transposed [k][r], padded
    __shared__ float Bs[32][132];  // [k][n], padded
    int tid = threadIdx.x;
    int tr = tid >> 4, tc = tid & 15;
    int row0 = blockIdx.x * 128;
    int col0 = blockIdx.y * 128;
    float acc[8][8];
#pragma unroll
    for (int i = 0; i < 8; ++i)
#pragma unroll
        for (int j = 0; j < 8; ++j) acc[i][j] = 0.f;

    for (int kc = 0; kc < 4; ++kc) {
        __syncthreads();
        // stage A (128 rows x 32 k), transposed, LN applied
#pragma unroll
        for (int u = 0; u < 4; ++u) {
            int flat = u * 256 + tid;
            int r = flat >> 3, c4 = flat & 7;
            int rc = row0 + r;
            int arow = CHUNKED ? ((rc / TCH) * TT + t0 + (rc % TCH)) : rc;
            float4 av = *(const float4*)(A + (size_t)arow * 128 + kc * 32 + c4 * 4);
            if (DO_LN) {
                float m_ = mu[arow], s_ = rs[arow];
                int k = kc * 32 + c4 * 4;
                float4 gv = *(const float4*)(lng + k);
                float4 bv = *(const float4*)(lnb + k);
                av.x = (av.x - m_) * s_ * gv.x + bv.x;
                av.y = (av.y - m_) * s_ * gv.y + bv.y;
                av.z = (av.z - m_) * s_ * gv.z + bv.z;
                av.w = (av.w - m_) * s_ * gv.w + bv.w;
            }
            int kl = c4 * 4;
            As[kl + 0][r] = av.x;
            As[kl + 1][r] = av.y;
            As[kl + 2][r] = av.z;
            As[kl + 3][r] = av.w;
        }
        // stage B (32 k x 128 n)
#pragma unroll
        for (int u = 0; u < 4; ++u) {
            int flat = u * 256 + tid;
            int k = flat >> 5, n4 = flat & 31;
            float4 bv = *(const float4*)(Bw + (size_t)(kc * 32 + k) * ldb + col0 + n4 * 4);
            *(float4*)&Bs[k][n4 * 4] = bv;
        }
        __syncthreads();
#pragma unroll
        for (int kk = 0; kk < 32; ++kk) {
            float4 a0 = *(const float4*)&As[kk][tr * 8];
            float4 a1 = *(const float4*)&As[kk][tr * 8 + 4];
            float4 b0 = *(const float4*)&Bs[kk][tc * 8];
            float4 b1 = *(const float4*)&Bs[kk][tc * 8 + 4];
            float a[8] = {a0.x, a0.y, a0.z, a0.w, a1.x, a1.y, a1.z, a1.w};
            float b[8] = {b0.x, b0.y, b0.z, b0.w, b1.x, b1.y, b1.z, b1.w};
#pragma unroll
            for (int i = 0; i < 8; ++i)
#pragma unroll
                for (int j = 0; j < 8; ++j) acc[i][j] = fmaf(a[i], b[j], acc[i][j]);
        }
    }
    // epilogue
#pragma unroll
    for (int i = 0; i < 8; ++i) {
        int rc = row0 + tr * 8 + i;
        float* Crow = C + (size_t)rc * ldc + col0 + tc * 8;
#pragma unroll
        for (int j2 = 0; j2 < 2; ++j2) {
            float v0 = acc[i][j2 * 4 + 0], v1 = acc[i][j2 * 4 + 1];
            float v2 = acc[i][j2 * 4 + 2], v3 = acc[i][j2 * 4 + 3];
            if (bias) {
                float4 bb = *(const float4*)(bias + col0 + tc * 8 + j2 * 4);
                v0 += bb.x; v1 += bb.y; v2 += bb.z; v3 += bb.w;
            }
            if (EPI == 1) {
                float u0 = 0.7978845608028654f * (v0 + 0.044715f * v0 * v0 * v0);
                float u1 = 0.7978845608028654f * (v1 + 0.044715f * v1 * v1 * v1);
                float u2 = 0.7978845608028654f * (v2 + 0.044715f * v2 * v2 * v2);
                float u3 = 0.7978845608028654f * (v3 + 0.044715f * v3 * v3 * v3);
                v0 = 0.5f * v0 * (1.f + tanhf(u0));
                v1 = 0.5f * v1 * (1.f + tanhf(u1));
                v2 = 0.5f * v2 * (1.f + tanhf(u2));
                v3 = 0.5f * v3 * (1.f + tanhf(u3));
            }
            if (EPI == 2) {
                float4 old = *(const float4*)(Crow + j2 * 4);
                v0 += old.x; v1 += old.y; v2 += old.z; v3 += old.w;
            }
            float4 vv = make_float4(v0, v1, v2, v3);
            *(float4*)(Crow + j2 * 4) = vv;
        }
    }
}

// ---------------- sLSTM scan over one T-chunk, fused GroupNorm + residual ----------------
// 8 batches / wg; thread: d = tid&127, j = tid>>7 handles 4 batches. R in registers.
__global__ __launch_bounds__(256, 2) void k_slstm(
    const float* __restrict__ xg, float* __restrict__ h,
    const float* __restrict__ Rg, const float* __restrict__ gng, const float* __restrict__ gnb,
    float* __restrict__ cs, float* __restrict__ ns, float* __restrict__ ms,
    float* __restrict__ hsb, int t0) {
    int tid = threadIdx.x;
    int d = tid & 127;
    int j = tid >> 7;
    int hh = d >> 5, e = d & 31;
    int b0 = blockIdx.x * 8;
    int lb0 = j * 4;

    float Rr[4][32];  // R[g][hh][dd][e] for this thread's (hh, e)
#pragma unroll
    for (int g = 0; g < 4; ++g)
#pragma unroll
        for (int dd = 0; dd < 32; ++dd)
            Rr[g][dd] = Rg[(size_t)((g * 4 + hh) * 32 + dd) * 32 + e];

    __shared__ float hl[2][8][128];
    float c[4], n[4], m[4];
    if (t0 == 0) {
#pragma unroll
        for (int i = 0; i < 4; ++i) {
            c[i] = 0.f; n[i] = 0.f; m[i] = 0.f;
            hl[0][lb0 + i][d] = 0.f;
        }
    } else {
#pragma unroll
        for (int i = 0; i < 4; ++i) {
            size_t si = (size_t)(b0 + lb0 + i) * 128 + d;
            c[i] = cs[si]; n[i] = ns[si]; m[i] = ms[si];
            hl[0][lb0 + i][d] = hsb[si];
        }
    }
    float gg = gng[d], gb = gnb[d];
    __syncthreads();
    int cur = 0;
    for (int tl = 0; tl < TCH; ++tl) {
        float xgv[4][4];
#pragma unroll
        for (int i = 0; i < 4; ++i)
#pragma unroll
            for (int g = 0; g < 4; ++g)
                xgv[i][g] = xg[((size_t)(b0 + lb0 + i) * TCH + tl) * 512 + g * 128 + d];
#pragma unroll
        for (int i = 0; i < 4; ++i) {
            int lb = lb0 + i;
            float r0 = 0.f, r1 = 0.f, r2 = 0.f, r3 = 0.f;
            const float* hrow = hl[cur][lb];
#pragma unroll
            for (int dd = 0; dd < 32; ++dd) {
                float hv = hrow[hh * 32 + dd];
                r0 = fmaf(hv, Rr[0][dd], r0);
                r1 = fmaf(hv, Rr[1][dd], r1);
                r2 = fmaf(hv, Rr[2][dd], r2);
                r3 = fmaf(hv, Rr[3][dd], r3);
            }
            float it = xgv[i][0] + r0;
            float ft = xgv[i][1] + r1;
            float zt = xgv[i][2] + r2;
            float ot = xgv[i][3] + r3;
            float mn = fmaxf(ft + m[i], it);
            float iv = __expf(it - mn);
            float fv = __expf(ft + m[i] - mn);
            float cn = fv * c[i] + iv * tanhf(zt);
            float nn = fv * n[i] + iv;
            float hv = cn / (nn * (1.f + __expf(-ot)));  // sigmoid(ot)*c/n
            c[i] = cn; n[i] = nn; m[i] = mn;
            // GroupNorm over the 32 lanes of this head
            float s = hv, ss = hv * hv;
#pragma unroll
            for (int off = 1; off < 32; off <<= 1) {
                s += __shfl_xor(s, off);
                ss += __shfl_xor(ss, off);
            }
            float mu_ = s * (1.f / 32.f);
            float var_ = ss * (1.f / 32.f) - mu_ * mu_;
            float xn = (hv - mu_) * rsqrtf(var_ + EPS);
            size_t hidx = ((size_t)(b0 + lb) * TT + t0 + tl) * 128 + d;
            h[hidx] += xn * gg + gb;
            hl[cur ^ 1][lb][d] = hv;
        }
        __syncthreads();
        cur ^= 1;
    }
#pragma unroll
    for (int i = 0; i < 4; ++i) {
        size_t si = (size_t)(b0 + lb0 + i) * 128 + d;
        cs[si] = c[i]; ns[si] = n[i]; ms[si] = m[i];
        hsb[si] = hl[cur][lb0 + i][d];
    }
}

// ---------------- final LN (t=T-1 only) + matvec ----------------
__global__ __launch_bounds__(256) void k_out(const float* __restrict__ h,
                                             const float* __restrict__ lnfg,
                                             const float* __restrict__ lnfb,
                                             const float* __restrict__ w_out,
                                             const float* __restrict__ b_out,
                                             float* __restrict__ out) {
    int b = blockIdx.x * 4 + (threadIdx.x >> 6);
    int l = threadIdx.x & 63;
    const float* hr = h + ((size_t)b * TT + (TT - 1)) * 128;
    float2 v = *(const float2*)(hr + l * 2);
    float s = v.x + v.y, ss = v.x * v.x + v.y * v.y;
#pragma unroll
    for (int off = 1; off < 64; off <<= 1) {
        s += __shfl_xor(s, off);
        ss += __shfl_xor(ss, off);
    }
    float mu_ = s * (1.f / 128.f);
    float rstd = rsqrtf(ss * (1.f / 128.f) - mu_ * mu_ + EPS);
    float2 g = *(const float2*)(lnfg + l * 2);
    float2 bb = *(const float2*)(lnfb + l * 2);
    float2 w = *(const float2*)(w_out + l * 2);
    float dot = ((v.x - mu_) * rstd * g.x + bb.x) * w.x +
                ((v.y - mu_) * rstd * g.y + bb.y) * w.y;
#pragma unroll
    for (int off = 1; off < 64; off <<= 1) dot += __shfl_xor(dot, off);
    if (l == 0) out[b] = dot + b_out[0];
}

extern "C" void kernel_launch(void* const* d_in, const int* in_sizes, int n_in,
                              void* d_out, int out_size, void* d_ws, size_t ws_size,
                              hipStream_t stream) {
    const float* x    = (const float*)d_in[0];
    const float* w_in = (const float*)d_in[1];
    const float* b_in = (const float*)d_in[2];
    const float* ln1g = (const float*)d_in[3];
    const float* ln1b = (const float*)d_in[4];
    const float* Wg   = (const float*)d_in[5];
    const float* bg   = (const float*)d_in[6];
    const float* Rg   = (const float*)d_in[7];
    const float* gng  = (const float*)d_in[8];
    const float* gnb  = (const float*)d_in[9];
    const float* ln2g = (const float*)d_in[10];
    const float* ln2b = (const float*)d_in[11];
    const float* W1   = (const float*)d_in[12];
    const float* W2   = (const float*)d_in[13];
    const float* lnfg = (const float*)d_in[14];
    const float* lnfb = (const float*)d_in[15];
    const float* wout = (const float*)d_in[16];
    const float* bout = (const float*)d_in[17];
    float* out = (float*)d_out;

    // workspace layout (floats): h | xg_chunk(=t1) | mu | rs | c | n | m | hstate
    // h: 33.55M, xg: 16.78M (TCH=8), mu/rs: 0.26M each, states: 0.52M each
    // total = 211.3 MB  (kept < 256 MiB — round-1 crash was ws overflow at 279 MB)
    float* W   = (float*)d_ws;
    float* h   = W;
    float* xg  = h + (size_t)MROWS * 128;
    float* mu  = xg + (size_t)(BB * TCH) * 512;
    float* rs  = mu + MROWS;
    float* cs  = rs + MROWS;
    float* ns  = cs + (size_t)BB * 128;
    float* ms  = ns + (size_t)BB * 128;
    float* hsb = ms + (size_t)BB * 128;

    k_embed<<<MROWS * 128 / 256, 256, 0, stream>>>(x, w_in, b_in, h);

    for (int blk = 0; blk < NBLK; ++blk) {
        // LN1 stats over pre-update h (valid for all chunks: slstm only writes rows
        // whose gate GEMM has already consumed them)
        k_stats<<<MROWS / 4, 256, 0, stream>>>(h, mu, rs);
        for (int tc = 0; tc < NCHUNK; ++tc) {
            dim3 g1(BB * TCH / 128, 4);
            k_gemm<true, true, 0><<<g1, 256, 0, stream>>>(
                h, Wg + (size_t)blk * 128 * 512, mu, rs, ln1g + blk * 128,
                ln1b + blk * 128, bg + blk * 512, xg, 512, 512, tc * TCH);
            k_slstm<<<BB / 8, 256, 0, stream>>>(
                xg, h, Rg + (size_t)blk * 16384, gng + blk * 128, gnb + blk * 128,
                cs, ns, ms, hsb, tc * TCH);
        }
        // FFN: t1 = gelu(LN2(h) @ W1); h += t1 @ W2   (t1 reuses xg buffer, needs
        // MROWS*128 = 33.55M floats > xg 16.78M? NO — split into two M-halves)
        k_stats<<<MROWS / 4, 256, 0, stream>>>(h, mu, rs);
        for (int half = 0; half < 2; ++half) {
            size_t r0 = (size_t)half * (MROWS / 2);
            dim3 g2(MROWS / 2 / 128, 1);
            k_gemm<true, false, 1><<<g2, 256, 0, stream>>>(
                h + r0 * 128, W1 + (size_t)blk * 16384, mu + r0, rs + r0,
                ln2g + blk * 128, ln2b + blk * 128, nullptr, xg, 128, 128, 0);
            k_gemm<false, false, 2><<<g2, 256, 0, stream>>>(
                xg, W2 + (size_t)blk * 16384, nullptr, nullptr, nullptr, nullptr,
                nullptr, h + r0 * 128, 128, 128, 0);
        }
    }
    k_out<<<BB / 4, 256, 0, stream>>>(h, lnfg, lnfb, wout, bout, out);
}

// Round 3
// 1475.114 us; speedup vs baseline: 1.6030x; 1.6030x over previous
//
#include <hip/hip_runtime.h>
#include <hip/hip_bf16.h>
#include <cstdint>
#include <cstddef>

#define EPS 1e-5f
#define BB 4096
#define TT 64
#define NBLK 2
#define TCH 16
#define NCHUNK (TT / TCH)
#define MROWS (BB * TT)

typedef unsigned short ushort_t;
typedef __attribute__((ext_vector_type(8))) short short8;
typedef __attribute__((ext_vector_type(4))) float floatx4;

__device__ __forceinline__ ushort_t f2b(float f) {
    __hip_bfloat16 h = __float2bfloat16(f);
    return *reinterpret_cast<ushort_t*>(&h);
}
__device__ __forceinline__ float b2f(ushort_t u) {
    unsigned int x = ((unsigned int)u) << 16;
    return __uint_as_float(x);
}

// ---------------- embed: h = x @ w_in + b_in ----------------
__global__ __launch_bounds__(256) void k_embed(const float* __restrict__ x,
                                               const float* __restrict__ w_in,
                                               const float* __restrict__ b_in,
                                               float* __restrict__ h) {
    int idx = blockIdx.x * 256 + threadIdx.x;
    int row = idx >> 7, d = idx & 127;
    const float* xr = x + (size_t)row * 3;
    h[idx] = xr[0] * w_in[d] + xr[1] * w_in[128 + d] + xr[2] * w_in[256 + d] + b_in[d];
}

// ---------------- per-row LN stats (mu, rstd) ----------------
__global__ __launch_bounds__(256) void k_stats(const float* __restrict__ h,
                                               float* __restrict__ mu,
                                               float* __restrict__ rs) {
    int row = blockIdx.x * 4 + (threadIdx.x >> 6);
    int l = threadIdx.x & 63;
    float2 v = *(const float2*)(h + (size_t)row * 128 + l * 2);
    float s = v.x + v.y, ss = v.x * v.x + v.y * v.y;
#pragma unroll
    for (int off = 1; off < 64; off <<= 1) {
        s += __shfl_xor(s, off);
        ss += __shfl_xor(ss, off);
    }
    if (l == 0) {
        float m_ = s * (1.f / 128.f);
        mu[row] = m_;
        rs[row] = rsqrtf(ss * (1.f / 128.f) - m_ * m_ + EPS);
    }
}

// ---------------- weight convert+transpose: dst[n][k] = bf16(src[k][n]) ----------------
__global__ __launch_bounds__(256) void k_cvtw(const float* __restrict__ src,
                                              ushort_t* __restrict__ dst, int N) {
    int idx = blockIdx.x * 256 + threadIdx.x;  // over N*128 (dst order)
    int n = idx >> 7, k = idx & 127;
    dst[idx] = f2b(src[(size_t)k * N + n]);
}

// ---------------- MFMA GEMM: C = [LN(A)] @ B (+bias) (+gelu | +=res) ----------------
// 128x128 tile, K=128 in one LDS stage, 4 waves each computing 64x64 via
// 4x4 grid of 16x16x32 bf16 MFMAs over 4 k-steps.
// A_BF: A already bf16 [m][k]. CHUNKED: A row rc -> h row (rc/16)*64+t0+(rc%16).
// EPI: 0 = bias+store bf16, 1 = gelu+store bf16, 2 = Cf += acc (fp32)
template <bool A_BF, bool DO_LN, bool CHUNKED, int EPI>
__global__ __launch_bounds__(256, 2) void k_mgemm(
    const float* __restrict__ A, const ushort_t* __restrict__ Ab,
    const ushort_t* __restrict__ Bt,
    const float* __restrict__ mu, const float* __restrict__ rs,
    const float* __restrict__ lng, const float* __restrict__ lnb,
    const float* __restrict__ bias, ushort_t* __restrict__ Cb,
    float* __restrict__ Cf, int N, int t0) {
    __shared__ ushort_t As[128][136];  // [m][k], +8 pad
    __shared__ ushort_t Bs[128][136];  // [n][k], +8 pad
    int tid = threadIdx.x;
    int row0 = blockIdx.x * 128;
    int col0 = blockIdx.y * 128;

    if (A_BF) {
        // A already bf16 row-major [m][k]
#pragma unroll
        for (int u = 0; u < 8; ++u) {
            int flat = u * 256 + tid;
            int r = flat >> 4, c = (flat & 15) * 8;
            uint4 av = *(const uint4*)(Ab + (size_t)(row0 + r) * 128 + c);
            *(uint4*)&As[r][c] = av;
        }
    } else {
#pragma unroll
        for (int u = 0; u < 16; ++u) {
            int flat = u * 256 + tid;
            int r = flat >> 5, k = (flat & 31) * 4;
            int rc = row0 + r;
            int arow = CHUNKED ? ((rc >> 4) * TT + t0 + (rc & 15)) : rc;
            float4 av = *(const float4*)(A + (size_t)arow * 128 + k);
            if (DO_LN) {
                float m_ = mu[arow], s_ = rs[arow];
                float4 gv = *(const float4*)(lng + k);
                float4 bv = *(const float4*)(lnb + k);
                av.x = (av.x - m_) * s_ * gv.x + bv.x;
                av.y = (av.y - m_) * s_ * gv.y + bv.y;
                av.z = (av.z - m_) * s_ * gv.z + bv.z;
                av.w = (av.w - m_) * s_ * gv.w + bv.w;
            }
            ushort_t* p = &As[r][k];
            p[0] = f2b(av.x); p[1] = f2b(av.y); p[2] = f2b(av.z); p[3] = f2b(av.w);
        }
    }
    // stage B: Bt is [Ntotal][128] bf16 row-major
#pragma unroll
    for (int u = 0; u < 8; ++u) {
        int flat = u * 256 + tid;
        int n = flat >> 4, c = (flat & 15) * 8;
        uint4 bv = *(const uint4*)(Bt + (size_t)(col0 + n) * 128 + c);
        *(uint4*)&Bs[n][c] = bv;
    }
    __syncthreads();

    int lane = tid & 63, wave = tid >> 6;
    int wm = (wave & 1) * 64, wn = (wave >> 1) * 64;
    int ml = lane & 15, quad = lane >> 4;
    floatx4 acc[4][4];
#pragma unroll
    for (int i = 0; i < 4; ++i)
#pragma unroll
        for (int j = 0; j < 4; ++j) acc[i][j] = (floatx4)0.f;

#pragma unroll
    for (int s = 0; s < 4; ++s) {
        short8 a[4], b[4];
#pragma unroll
        for (int i = 0; i < 4; ++i)
            a[i] = *(const short8*)&As[wm + i * 16 + ml][s * 32 + quad * 8];
#pragma unroll
        for (int j = 0; j < 4; ++j)
            b[j] = *(const short8*)&Bs[wn + j * 16 + ml][s * 32 + quad * 8];
#pragma unroll
        for (int i = 0; i < 4; ++i)
#pragma unroll
            for (int j = 0; j < 4; ++j)
                acc[i][j] = __builtin_amdgcn_mfma_f32_16x16x32_bf16(
                    a[i], b[j], acc[i][j], 0, 0, 0);
    }

    // epilogue: C[row][col], row = quad*4+reg, col = lane&15 (m91-verified)
#pragma unroll
    for (int i = 0; i < 4; ++i) {
#pragma unroll
        for (int j = 0; j < 4; ++j) {
            int cc = col0 + wn + j * 16 + ml;
            float bv = bias ? bias[cc] : 0.f;
#pragma unroll
            for (int r = 0; r < 4; ++r) {
                int rr = row0 + wm + i * 16 + quad * 4 + r;
                float v = acc[i][j][r] + bv;
                if (EPI == 1) {
                    float uu = 0.7978845608028654f * (v + 0.044715f * v * v * v);
                    v = 0.5f * v * (1.f + tanhf(uu));
                }
                if (EPI == 2) {
                    size_t o = (size_t)rr * N + cc;
                    Cf[o] += v;
                } else {
                    Cb[(size_t)rr * N + cc] = f2b(v);
                }
            }
        }
    }
}

// ---------------- sLSTM scan over one T-chunk, fused GroupNorm + residual ----------------
__global__ __launch_bounds__(256, 2) void k_slstm(
    const ushort_t* __restrict__ xg, float* __restrict__ h,
    const float* __restrict__ Rg, const float* __restrict__ gng, const float* __restrict__ gnb,
    float* __restrict__ cs, float* __restrict__ ns, float* __restrict__ ms,
    float* __restrict__ hsb, int t0) {
    int tid = threadIdx.x;
    int d = tid & 127;
    int j = tid >> 7;
    int hh = d >> 5, e = d & 31;
    int b0 = blockIdx.x * 8;
    int lb0 = j * 4;

    float Rr[4][32];  // R[g][hh][dd][e] for this thread's (hh, e)
#pragma unroll
    for (int g = 0; g < 4; ++g)
#pragma unroll
        for (int dd = 0; dd < 32; ++dd)
            Rr[g][dd] = Rg[(size_t)((g * 4 + hh) * 32 + dd) * 32 + e];

    __shared__ float hl[2][8][128];
    float c[4], n[4], m[4];
    if (t0 == 0) {
#pragma unroll
        for (int i = 0; i < 4; ++i) {
            c[i] = 0.f; n[i] = 0.f; m[i] = 0.f;
            hl[0][lb0 + i][d] = 0.f;
        }
    } else {
#pragma unroll
        for (int i = 0; i < 4; ++i) {
            size_t si = (size_t)(b0 + lb0 + i) * 128 + d;
            c[i] = cs[si]; n[i] = ns[si]; m[i] = ms[si];
            hl[0][lb0 + i][d] = hsb[si];
        }
    }
    float gg = gng[d], gb = gnb[d];
    __syncthreads();
    int cur = 0;
    for (int tl = 0; tl < TCH; ++tl) {
        float xgv[4][4];
#pragma unroll
        for (int i = 0; i < 4; ++i)
#pragma unroll
            for (int g = 0; g < 4; ++g)
                xgv[i][g] = b2f(xg[((size_t)(b0 + lb0 + i) * TCH + tl) * 512 + g * 128 + d]);
#pragma unroll
        for (int i = 0; i < 4; ++i) {
            int lb = lb0 + i;
            float r0 = 0.f, r1 = 0.f, r2 = 0.f, r3 = 0.f;
            const float* hrow = hl[cur][lb];
#pragma unroll
            for (int dd = 0; dd < 32; ++dd) {
                float hv = hrow[hh * 32 + dd];
                r0 = fmaf(hv, Rr[0][dd], r0);
                r1 = fmaf(hv, Rr[1][dd], r1);
                r2 = fmaf(hv, Rr[2][dd], r2);
                r3 = fmaf(hv, Rr[3][dd], r3);
            }
            float it = xgv[i][0] + r0;
            float ft = xgv[i][1] + r1;
            float zt = xgv[i][2] + r2;
            float ot = xgv[i][3] + r3;
            float mn = fmaxf(ft + m[i], it);
            float iv = __expf(it - mn);
            float fv = __expf(ft + m[i] - mn);
            float cn = fv * c[i] + iv * tanhf(zt);
            float nn = fv * n[i] + iv;
            float hv = cn / (nn * (1.f + __expf(-ot)));  // sigmoid(ot)*c/n
            c[i] = cn; n[i] = nn; m[i] = mn;
            // GroupNorm over the 32 lanes of this head
            float s = hv, ss = hv * hv;
#pragma unroll
            for (int off = 1; off < 32; off <<= 1) {
                s += __shfl_xor(s, off);
                ss += __shfl_xor(ss, off);
            }
            float mu_ = s * (1.f / 32.f);
            float var_ = ss * (1.f / 32.f) - mu_ * mu_;
            float xn = (hv - mu_) * rsqrtf(var_ + EPS);
            size_t hidx = ((size_t)(b0 + lb) * TT + t0 + tl) * 128 + d;
            h[hidx] += xn * gg + gb;
            hl[cur ^ 1][lb][d] = hv;
        }
        __syncthreads();
        cur ^= 1;
    }
#pragma unroll
    for (int i = 0; i < 4; ++i) {
        size_t si = (size_t)(b0 + lb0 + i) * 128 + d;
        cs[si] = c[i]; ns[si] = n[i]; ms[si] = m[i];
        hsb[si] = hl[cur][lb0 + i][d];
    }
}

// ---------------- final LN (t=T-1 only) + matvec ----------------
__global__ __launch_bounds__(256) void k_out(const float* __restrict__ h,
                                             const float* __restrict__ lnfg,
                                             const float* __restrict__ lnfb,
                                             const float* __restrict__ w_out,
                                             const float* __restrict__ b_out,
                                             float* __restrict__ out) {
    int b = blockIdx.x * 4 + (threadIdx.x >> 6);
    int l = threadIdx.x & 63;
    const float* hr = h + ((size_t)b * TT + (TT - 1)) * 128;
    float2 v = *(const float2*)(hr + l * 2);
    float s = v.x + v.y, ss = v.x * v.x + v.y * v.y;
#pragma unroll
    for (int off = 1; off < 64; off <<= 1) {
        s += __shfl_xor(s, off);
        ss += __shfl_xor(ss, off);
    }
    float mu_ = s * (1.f / 128.f);
    float rstd = rsqrtf(ss * (1.f / 128.f) - mu_ * mu_ + EPS);
    float2 g = *(const float2*)(lnfg + l * 2);
    float2 bb = *(const float2*)(lnfb + l * 2);
    float2 w = *(const float2*)(w_out + l * 2);
    float dot = ((v.x - mu_) * rstd * g.x + bb.x) * w.x +
                ((v.y - mu_) * rstd * g.y + bb.y) * w.y;
#pragma unroll
    for (int off = 1; off < 64; off <<= 1) dot += __shfl_xor(dot, off);
    if (l == 0) out[b] = dot + b_out[0];
}

extern "C" void kernel_launch(void* const* d_in, const int* in_sizes, int n_in,
                              void* d_out, int out_size, void* d_ws, size_t ws_size,
                              hipStream_t stream) {
    const float* x    = (const float*)d_in[0];
    const float* w_in = (const float*)d_in[1];
    const float* b_in = (const float*)d_in[2];
    const float* ln1g = (const float*)d_in[3];
    const float* ln1b = (const float*)d_in[4];
    const float* Wg   = (const float*)d_in[5];
    const float* bg   = (const float*)d_in[6];
    const float* Rg   = (const float*)d_in[7];
    const float* gng  = (const float*)d_in[8];
    const float* gnb  = (const float*)d_in[9];
    const float* ln2g = (const float*)d_in[10];
    const float* ln2b = (const float*)d_in[11];
    const float* W1   = (const float*)d_in[12];
    const float* W2   = (const float*)d_in[13];
    const float* lnfg = (const float*)d_in[14];
    const float* lnfb = (const float*)d_in[15];
    const float* wout = (const float*)d_in[16];
    const float* bout = (const float*)d_in[17];
    float* out = (float*)d_out;

    // ws layout: h fp32 (134.2MB) | xg bf16 chunk / t1b (67.1MB) | mu | rs |
    // cs | ns | ms | hsb | Wgt | W1t | W2t   total ~212 MB < 256 MiB
    float* h = (float*)d_ws;
    ushort_t* xg = (ushort_t*)(h + (size_t)MROWS * 128);
    float* mu = (float*)(xg + (size_t)BB * TCH * 512);
    float* rs = mu + MROWS;
    float* cs = rs + MROWS;
    float* ns = cs + (size_t)BB * 128;
    float* ms = ns + (size_t)BB * 128;
    float* hsb = ms + (size_t)BB * 128;
    ushort_t* Wgt = (ushort_t*)(hsb + (size_t)BB * 128);  // [blk][512][128]
    ushort_t* W1t = Wgt + 2 * 512 * 128;                  // [blk][128][128]
    ushort_t* W2t = W1t + 2 * 128 * 128;

    // weight cast+transpose (tiny)
    for (int blk = 0; blk < NBLK; ++blk) {
        k_cvtw<<<512 * 128 / 256, 256, 0, stream>>>(Wg + (size_t)blk * 128 * 512,
                                                    Wgt + (size_t)blk * 512 * 128, 512);
        k_cvtw<<<128 * 128 / 256, 256, 0, stream>>>(W1 + (size_t)blk * 16384,
                                                    W1t + (size_t)blk * 16384, 128);
        k_cvtw<<<128 * 128 / 256, 256, 0, stream>>>(W2 + (size_t)blk * 16384,
                                                    W2t + (size_t)blk * 16384, 128);
    }

    k_embed<<<MROWS * 128 / 256, 256, 0, stream>>>(x, w_in, b_in, h);

    for (int blk = 0; blk < NBLK; ++blk) {
        k_stats<<<MROWS / 4, 256, 0, stream>>>(h, mu, rs);
        for (int tc = 0; tc < NCHUNK; ++tc) {
            dim3 g1(BB * TCH / 128, 4);
            k_mgemm<false, true, true, 0><<<g1, 256, 0, stream>>>(
                h, nullptr, Wgt + (size_t)blk * 512 * 128, mu, rs,
                ln1g + blk * 128, ln1b + blk * 128, bg + blk * 512,
                xg, nullptr, 512, tc * TCH);
            k_slstm<<<BB / 8, 256, 0, stream>>>(
                xg, h, Rg + (size_t)blk * 16384, gng + blk * 128, gnb + blk * 128,
                cs, ns, ms, hsb, tc * TCH);
        }
        // FFN: t1b = bf16(gelu(LN2(h) @ W1)); h += t1b @ W2  (t1b reuses xg buf)
        k_stats<<<MROWS / 4, 256, 0, stream>>>(h, mu, rs);
        dim3 g2(MROWS / 128, 1);
        k_mgemm<false, true, false, 1><<<g2, 256, 0, stream>>>(
            h, nullptr, W1t + (size_t)blk * 16384, mu, rs,
            ln2g + blk * 128, ln2b + blk * 128, nullptr, xg, nullptr, 128, 0);
        k_mgemm<true, false, false, 2><<<g2, 256, 0, stream>>>(
            nullptr, xg, W2t + (size_t)blk * 16384, nullptr, nullptr,
            nullptr, nullptr, nullptr, nullptr, h, 128, 0);
    }
    k_out<<<BB / 4, 256, 0, stream>>>(h, lnfg, lnfb, wout, bout, out);
}

// Round 4
// 718.187 us; speedup vs baseline: 3.2924x; 2.0539x over previous
//
#include <hip/hip_runtime.h>
#include <hip/hip_bf16.h>
#include <cstdint>
#include <cstddef>

#define EPS 1e-5f
#define BB 4096
#define TT 64
#define NBLK 2
#define MROWS (BB * TT)

typedef unsigned short ushort_t;
typedef __attribute__((ext_vector_type(8))) short short8;
typedef __attribute__((ext_vector_type(4))) float floatx4;

__device__ __forceinline__ ushort_t f2b(float f) {
    __hip_bfloat16 h = __float2bfloat16(f);
    return *reinterpret_cast<ushort_t*>(&h);
}
__device__ __forceinline__ float tanh_fast(float z) {
    return 1.f - 2.f / (__expf(2.f * z) + 1.f);
}

// ---------------- embed: h = x @ w_in + b_in ----------------
__global__ __launch_bounds__(256) void k_embed(const float* __restrict__ x,
                                               const float* __restrict__ w_in,
                                               const float* __restrict__ b_in,
                                               float* __restrict__ h) {
    int idx = blockIdx.x * 256 + threadIdx.x;
    int row = idx >> 7, d = idx & 127;
    const float* xr = x + (size_t)row * 3;
    h[idx] = xr[0] * w_in[d] + xr[1] * w_in[128 + d] + xr[2] * w_in[256 + d] + b_in[d];
}

// ---------------- weight convert+transpose: dst[n][k] = bf16(src[k][n]) ----------------
__global__ __launch_bounds__(256) void k_cvtw(const float* __restrict__ src,
                                              ushort_t* __restrict__ dst, int N) {
    int idx = blockIdx.x * 256 + threadIdx.x;  // over N*128 (dst order)
    int n = idx >> 7, k = idx & 127;
    dst[idx] = f2b(src[(size_t)k * N + n]);
}

// ---------------- fused gate-GEMM + sLSTM scan + GroupNorm + residual ----------------
// grid = BB/16 = 256 wgs, 256 thr (4 waves). Each wg owns 16 batches for all T.
// Wave w = gate g. Wg/R B-frags static in registers. Per step:
//   A: stage LN1(h_in) (inline stats) -> Afrag LDS (bf16, MFMA A-layout rows)
//   B: MFMA xg+r+bias -> fp32 exchange Xbuf
//   C: gate nonlinearities, GroupNorm (shfl), h' = h_in + gn -> global; h_new -> Hlds
__global__ __launch_bounds__(256, 1) void k_gslstm(
    float* __restrict__ h, const ushort_t* __restrict__ Wgt,
    const float* __restrict__ bg, const float* __restrict__ Rg,
    const float* __restrict__ ln1g, const float* __restrict__ ln1b,
    const float* __restrict__ gng, const float* __restrict__ gnb) {
    __shared__ ushort_t Afrag[16][136];  // LN1(h_in) bf16, [m][k], pad->16B-align rows
    __shared__ ushort_t Hlds[16][136];   // h_prev bf16, [m][k]
    __shared__ float Xbuf[16][516];      // gate preacts fp32, [b][g*128+d], pad 516

    int tid = threadIdx.x;
    int lane = tid & 63;
    int gate = tid >> 6;       // wave index = gate
    int q = lane >> 4, ml = lane & 15;
    int bo = tid >> 4;         // local batch (phase A/C ownership)
    int dl = tid & 15;         // d-octet: d = dl*8 .. dl*8+8
    int b0 = blockIdx.x * 16;

    // ---- static setup ----
    short8 WB[4][8];  // [k-slice][n-slice] of Wg for this gate
#pragma unroll
    for (int ks = 0; ks < 4; ++ks)
#pragma unroll
        for (int s = 0; s < 8; ++s)
            WB[ks][s] = *(const short8*)(Wgt +
                ((size_t)(gate * 128 + s * 16 + ml) * 128 + ks * 32 + q * 8));
    float biasv[8];
#pragma unroll
    for (int s = 0; s < 8; ++s) biasv[s] = bg[gate * 128 + s * 16 + ml];
    short8 RB[4][2];  // [head][n-slice], K=32
#pragma unroll
    for (int hh = 0; hh < 4; ++hh)
#pragma unroll
        for (int sr = 0; sr < 2; ++sr) {
            ushort_t tmp[8];
#pragma unroll
            for (int jj = 0; jj < 8; ++jj)
                tmp[jj] = f2b(Rg[((size_t)(gate * 4 + hh) * 32 + q * 8 + jj) * 32 +
                               sr * 16 + ml]);
            RB[hh][sr] = *(const short8*)tmp;
        }
    float lng_[8], lnb_[8], gng_[8], gnb_[8];
#pragma unroll
    for (int jj = 0; jj < 8; ++jj) {
        lng_[jj] = ln1g[dl * 8 + jj];
        lnb_[jj] = ln1b[dl * 8 + jj];
        gng_[jj] = gng[dl * 8 + jj];
        gnb_[jj] = gnb[dl * 8 + jj];
    }
    float cst[8], nst[8], mst[8];
#pragma unroll
    for (int jj = 0; jj < 8; ++jj) { cst[jj] = 0.f; nst[jj] = 0.f; mst[jj] = 0.f; }

    for (int i = tid; i < 16 * 136; i += 256) ((ushort_t*)Hlds)[i] = 0;

    float hin[8];
    {
        const float* p = h + ((size_t)(b0 + bo) * TT) * 128 + dl * 8;
        float4 v0 = *(const float4*)p;
        float4 v1 = *(const float4*)(p + 4);
        hin[0] = v0.x; hin[1] = v0.y; hin[2] = v0.z; hin[3] = v0.w;
        hin[4] = v1.x; hin[5] = v1.y; hin[6] = v1.z; hin[7] = v1.w;
    }
    __syncthreads();

    for (int t = 0; t < TT; ++t) {
        // ---- phase A: inline LN1 stats + Afrag stage + prefetch ----
        float s = 0.f, ss = 0.f;
#pragma unroll
        for (int jj = 0; jj < 8; ++jj) { s += hin[jj]; ss += hin[jj] * hin[jj]; }
#pragma unroll
        for (int off = 1; off < 16; off <<= 1) {
            s += __shfl_xor(s, off);
            ss += __shfl_xor(ss, off);
        }
        float mu = s * (1.f / 128.f);
        float rstd = rsqrtf(ss * (1.f / 128.f) - mu * mu + EPS);
        {
            ushort_t ab[8];
#pragma unroll
            for (int jj = 0; jj < 8; ++jj)
                ab[jj] = f2b((hin[jj] - mu) * rstd * lng_[jj] + lnb_[jj]);
            *(short8*)&Afrag[bo][dl * 8] = *(const short8*)ab;
        }
        float hin2[8];
        if (t + 1 < TT) {
            const float* p = h + ((size_t)(b0 + bo) * TT + t + 1) * 128 + dl * 8;
            float4 v0 = *(const float4*)p;
            float4 v1 = *(const float4*)(p + 4);
            hin2[0] = v0.x; hin2[1] = v0.y; hin2[2] = v0.z; hin2[3] = v0.w;
            hin2[4] = v1.x; hin2[5] = v1.y; hin2[6] = v1.z; hin2[7] = v1.w;
        } else {
#pragma unroll
            for (int jj = 0; jj < 8; ++jj) hin2[jj] = 0.f;
        }
        __syncthreads();  // b1: Afrag + Hlds(prev C) visible; Xbuf(prev) consumed

        // ---- phase B: MFMA xg + r + bias ----
        short8 af[4], hf[4];
#pragma unroll
        for (int ks = 0; ks < 4; ++ks)
            af[ks] = *(const short8*)&Afrag[ml][ks * 32 + q * 8];
#pragma unroll
        for (int hh = 0; hh < 4; ++hh)
            hf[hh] = *(const short8*)&Hlds[ml][hh * 32 + q * 8];
        floatx4 acc[8];
#pragma unroll
        for (int s8 = 0; s8 < 8; ++s8) {
            float b = biasv[s8];
            acc[s8] = (floatx4){b, b, b, b};
        }
#pragma unroll
        for (int ks = 0; ks < 4; ++ks)
#pragma unroll
            for (int s8 = 0; s8 < 8; ++s8)
                acc[s8] = __builtin_amdgcn_mfma_f32_16x16x32_bf16(
                    af[ks], WB[ks][s8], acc[s8], 0, 0, 0);
#pragma unroll
        for (int hh = 0; hh < 4; ++hh)
#pragma unroll
            for (int sr = 0; sr < 2; ++sr)
                acc[hh * 2 + sr] = __builtin_amdgcn_mfma_f32_16x16x32_bf16(
                    hf[hh], RB[hh][sr], acc[hh * 2 + sr], 0, 0, 0);
#pragma unroll
        for (int s8 = 0; s8 < 8; ++s8)
#pragma unroll
            for (int r = 0; r < 4; ++r)
                Xbuf[q * 4 + r][gate * 128 + s8 * 16 + ml] = acc[s8][r];
        __syncthreads();  // b2: Xbuf ready

        // ---- phase C: nonlinearities + GN + residual ----
        float it[8], ft[8], zt[8], ot[8];
        {
            float4 a0 = *(const float4*)&Xbuf[bo][0 * 128 + dl * 8];
            float4 a1 = *(const float4*)&Xbuf[bo][0 * 128 + dl * 8 + 4];
            it[0] = a0.x; it[1] = a0.y; it[2] = a0.z; it[3] = a0.w;
            it[4] = a1.x; it[5] = a1.y; it[6] = a1.z; it[7] = a1.w;
            float4 f0 = *(const float4*)&Xbuf[bo][1 * 128 + dl * 8];
            float4 f1 = *(const float4*)&Xbuf[bo][1 * 128 + dl * 8 + 4];
            ft[0] = f0.x; ft[1] = f0.y; ft[2] = f0.z; ft[3] = f0.w;
            ft[4] = f1.x; ft[5] = f1.y; ft[6] = f1.z; ft[7] = f1.w;
            float4 z0 = *(const float4*)&Xbuf[bo][2 * 128 + dl * 8];
            float4 z1 = *(const float4*)&Xbuf[bo][2 * 128 + dl * 8 + 4];
            zt[0] = z0.x; zt[1] = z0.y; zt[2] = z0.z; zt[3] = z0.w;
            zt[4] = z1.x; zt[5] = z1.y; zt[6] = z1.z; zt[7] = z1.w;
            float4 o0 = *(const float4*)&Xbuf[bo][3 * 128 + dl * 8];
            float4 o1 = *(const float4*)&Xbuf[bo][3 * 128 + dl * 8 + 4];
            ot[0] = o0.x; ot[1] = o0.y; ot[2] = o0.z; ot[3] = o0.w;
            ot[4] = o1.x; ot[5] = o1.y; ot[6] = o1.z; ot[7] = o1.w;
        }
        float hv[8];
#pragma unroll
        for (int jj = 0; jj < 8; ++jj) {
            float mn = fmaxf(ft[jj] + mst[jj], it[jj]);
            float iv = __expf(it[jj] - mn);
            float fv = __expf(ft[jj] + mst[jj] - mn);
            float cn = fv * cst[jj] + iv * tanh_fast(zt[jj]);
            float nn = fv * nst[jj] + iv;
            hv[jj] = cn / (nn * (1.f + __expf(-ot[jj])));
            cst[jj] = cn; nst[jj] = nn; mst[jj] = mn;
        }
        // GroupNorm over head (32 dims): local 8 + shfl over 4 lanes (dl bits 0-1)
        float s2 = 0.f, q2 = 0.f;
#pragma unroll
        for (int jj = 0; jj < 8; ++jj) { s2 += hv[jj]; q2 += hv[jj] * hv[jj]; }
        s2 += __shfl_xor(s2, 1); q2 += __shfl_xor(q2, 1);
        s2 += __shfl_xor(s2, 2); q2 += __shfl_xor(q2, 2);
        float mu2 = s2 * (1.f / 32.f);
        float rstd2 = rsqrtf(q2 * (1.f / 32.f) - mu2 * mu2 + EPS);
        {
            float o[8];
#pragma unroll
            for (int jj = 0; jj < 8; ++jj)
                o[jj] = hin[jj] + (hv[jj] - mu2) * rstd2 * gng_[jj] + gnb_[jj];
            float* po = h + ((size_t)(b0 + bo) * TT + t) * 128 + dl * 8;
            *(float4*)po = make_float4(o[0], o[1], o[2], o[3]);
            *(float4*)(po + 4) = make_float4(o[4], o[5], o[6], o[7]);
            ushort_t hb[8];
#pragma unroll
            for (int jj = 0; jj < 8; ++jj) hb[jj] = f2b(hv[jj]);
            *(short8*)&Hlds[bo][dl * 8] = *(const short8*)hb;
        }
#pragma unroll
        for (int jj = 0; jj < 8; ++jj) hin[jj] = hin2[jj];
        // no barrier here: next phase A only writes Afrag (disjoint); b1 orders
        // Hlds writes / Xbuf reuse before next phase B.
    }
}

// ---------------- fused FFN: h += gelu(LN2(h) @ W1) @ W2, stats inline ----------------
__global__ __launch_bounds__(256, 2) void k_ffn(
    float* __restrict__ h, const ushort_t* __restrict__ W1t,
    const ushort_t* __restrict__ W2t,
    const float* __restrict__ lng, const float* __restrict__ lnb) {
    __shared__ ushort_t As[128][136];
    __shared__ ushort_t T1[128][136];
    int tid = threadIdx.x;
    int lane = tid & 63, wave = tid >> 6;
    int q = lane >> 4, ml = lane & 15;
    int wm = (wave & 1) * 64, wn = (wave >> 1) * 64;
    size_t row0 = (size_t)blockIdx.x * 128;

    // inline LN2 stats: 2 threads per row
    int r = tid >> 1, hf = tid & 1;
    const float* hrow = h + (row0 + r) * 128 + hf * 64;
    float s = 0.f, ss = 0.f;
#pragma unroll
    for (int k = 0; k < 16; ++k) {
        float4 v = ((const float4*)hrow)[k];
        s += v.x + v.y + v.z + v.w;
        ss += v.x * v.x + v.y * v.y + v.z * v.z + v.w * v.w;
    }
    s += __shfl_xor(s, 1);
    ss += __shfl_xor(ss, 1);
    float mu = s * (1.f / 128.f);
    float rstd = rsqrtf(ss * (1.f / 128.f) - mu * mu + EPS);
#pragma unroll
    for (int kk = 0; kk < 8; ++kk) {
        float4 a = ((const float4*)hrow)[2 * kk];
        float4 b = ((const float4*)hrow)[2 * kk + 1];
        float4 g0 = *(const float4*)(lng + hf * 64 + kk * 8);
        float4 g1 = *(const float4*)(lng + hf * 64 + kk * 8 + 4);
        float4 b0 = *(const float4*)(lnb + hf * 64 + kk * 8);
        float4 b1 = *(const float4*)(lnb + hf * 64 + kk * 8 + 4);
        ushort_t p[8];
        p[0] = f2b((a.x - mu) * rstd * g0.x + b0.x);
        p[1] = f2b((a.y - mu) * rstd * g0.y + b0.y);
        p[2] = f2b((a.z - mu) * rstd * g0.z + b0.z);
        p[3] = f2b((a.w - mu) * rstd * g0.w + b0.w);
        p[4] = f2b((b.x - mu) * rstd * g1.x + b1.x);
        p[5] = f2b((b.y - mu) * rstd * g1.y + b1.y);
        p[6] = f2b((b.z - mu) * rstd * g1.z + b1.z);
        p[7] = f2b((b.w - mu) * rstd * g1.w + b1.w);
        *(short8*)&As[r][hf * 64 + kk * 8] = *(const short8*)p;
    }
    __syncthreads();

    // MFMA1: t1 = gelu(As @ W1)
    short8 W1B[4][4];  // [jn][ks]
#pragma unroll
    for (int jn = 0; jn < 4; ++jn)
#pragma unroll
        for (int ks = 0; ks < 4; ++ks)
            W1B[jn][ks] = *(const short8*)(W1t +
                ((size_t)(wn + jn * 16 + ml) * 128 + ks * 32 + q * 8));
    floatx4 acc1[4][4];
#pragma unroll
    for (int i = 0; i < 4; ++i)
#pragma unroll
        for (int j = 0; j < 4; ++j) acc1[i][j] = (floatx4)0.f;
#pragma unroll
    for (int ks = 0; ks < 4; ++ks) {
        short8 af[4];
#pragma unroll
        for (int im = 0; im < 4; ++im)
            af[im] = *(const short8*)&As[wm + im * 16 + ml][ks * 32 + q * 8];
#pragma unroll
        for (int im = 0; im < 4; ++im)
#pragma unroll
            for (int jn = 0; jn < 4; ++jn)
                acc1[im][jn] = __builtin_amdgcn_mfma_f32_16x16x32_bf16(
                    af[im], W1B[jn][ks], acc1[im][jn], 0, 0, 0);
    }
#pragma unroll
    for (int im = 0; im < 4; ++im)
#pragma unroll
        for (int jn = 0; jn < 4; ++jn)
#pragma unroll
            for (int rr = 0; rr < 4; ++rr) {
                float v = acc1[im][jn][rr];
                float u = 0.7978845608028654f * (v + 0.044715f * v * v * v);
                float gv = 0.5f * v * (1.f + tanh_fast(u));
                T1[wm + im * 16 + q * 4 + rr][wn + jn * 16 + ml] = f2b(gv);
            }
    __syncthreads();

    // MFMA2: h += T1 @ W2
    short8 W2B[4][4];
#pragma unroll
    for (int jn = 0; jn < 4; ++jn)
#pragma unroll
        for (int ks = 0; ks < 4; ++ks)
            W2B[jn][ks] = *(const short8*)(W2t +
                ((size_t)(wn + jn * 16 + ml) * 128 + ks * 32 + q * 8));
    floatx4 acc2[4][4];
#pragma unroll
    for (int i = 0; i < 4; ++i)
#pragma unroll
        for (int j = 0; j < 4; ++j) acc2[i][j] = (floatx4)0.f;
#pragma unroll
    for (int ks = 0; ks < 4; ++ks) {
        short8 af[4];
#pragma unroll
        for (int im = 0; im < 4; ++im)
            af[im] = *(const short8*)&T1[wm + im * 16 + ml][ks * 32 + q * 8];
#pragma unroll
        for (int im = 0; im < 4; ++im)
#pragma unroll
            for (int jn = 0; jn < 4; ++jn)
                acc2[im][jn] = __builtin_amdgcn_mfma_f32_16x16x32_bf16(
                    af[im], W2B[jn][ks], acc2[im][jn], 0, 0, 0);
    }
#pragma unroll
    for (int im = 0; im < 4; ++im)
#pragma unroll
        for (int jn = 0; jn < 4; ++jn)
#pragma unroll
            for (int rr = 0; rr < 4; ++rr) {
                size_t rw = row0 + wm + im * 16 + q * 4 + rr;
                int cc = wn + jn * 16 + ml;
                h[rw * 128 + cc] += acc2[im][jn][rr];
            }
}

// ---------------- final LN (t=T-1 only) + matvec ----------------
__global__ __launch_bounds__(256) void k_out(const float* __restrict__ h,
                                             const float* __restrict__ lnfg,
                                             const float* __restrict__ lnfb,
                                             const float* __restrict__ w_out,
                                             const float* __restrict__ b_out,
                                             float* __restrict__ out) {
    int b = blockIdx.x * 4 + (threadIdx.x >> 6);
    int l = threadIdx.x & 63;
    const float* hr = h + ((size_t)b * TT + (TT - 1)) * 128;
    float2 v = *(const float2*)(hr + l * 2);
    float s = v.x + v.y, ss = v.x * v.x + v.y * v.y;
#pragma unroll
    for (int off = 1; off < 64; off <<= 1) {
        s += __shfl_xor(s, off);
        ss += __shfl_xor(ss, off);
    }
    float mu_ = s * (1.f / 128.f);
    float rstd = rsqrtf(ss * (1.f / 128.f) - mu_ * mu_ + EPS);
    float2 g = *(const float2*)(lnfg + l * 2);
    float2 bb = *(const float2*)(lnfb + l * 2);
    float2 w = *(const float2*)(w_out + l * 2);
    float dot = ((v.x - mu_) * rstd * g.x + bb.x) * w.x +
                ((v.y - mu_) * rstd * g.y + bb.y) * w.y;
#pragma unroll
    for (int off = 1; off < 64; off <<= 1) dot += __shfl_xor(dot, off);
    if (l == 0) out[b] = dot + b_out[0];
}

extern "C" void kernel_launch(void* const* d_in, const int* in_sizes, int n_in,
                              void* d_out, int out_size, void* d_ws, size_t ws_size,
                              hipStream_t stream) {
    const float* x    = (const float*)d_in[0];
    const float* w_in = (const float*)d_in[1];
    const float* b_in = (const float*)d_in[2];
    const float* ln1g = (const float*)d_in[3];
    const float* ln1b = (const float*)d_in[4];
    const float* Wg   = (const float*)d_in[5];
    const float* bg   = (const float*)d_in[6];
    const float* Rg   = (const float*)d_in[7];
    const float* gng  = (const float*)d_in[8];
    const float* gnb  = (const float*)d_in[9];
    const float* ln2g = (const float*)d_in[10];
    const float* ln2b = (const float*)d_in[11];
    const float* W1   = (const float*)d_in[12];
    const float* W2   = (const float*)d_in[13];
    const float* lnfg = (const float*)d_in[14];
    const float* lnfb = (const float*)d_in[15];
    const float* wout = (const float*)d_in[16];
    const float* bout = (const float*)d_in[17];
    float* out = (float*)d_out;

    // ws: h fp32 (134.2 MB) | Wgt bf16 [blk][512][128] | W1t | W2t  (~134.6 MB)
    float* h = (float*)d_ws;
    ushort_t* Wgt = (ushort_t*)(h + (size_t)MROWS * 128);
    ushort_t* W1t = Wgt + 2 * 512 * 128;
    ushort_t* W2t = W1t + 2 * 128 * 128;

    for (int blk = 0; blk < NBLK; ++blk) {
        k_cvtw<<<512 * 128 / 256, 256, 0, stream>>>(Wg + (size_t)blk * 128 * 512,
                                                    Wgt + (size_t)blk * 512 * 128, 512);
        k_cvtw<<<128 * 128 / 256, 256, 0, stream>>>(W1 + (size_t)blk * 16384,
                                                    W1t + (size_t)blk * 16384, 128);
        k_cvtw<<<128 * 128 / 256, 256, 0, stream>>>(W2 + (size_t)blk * 16384,
                                                    W2t + (size_t)blk * 16384, 128);
    }

    k_embed<<<MROWS * 128 / 256, 256, 0, stream>>>(x, w_in, b_in, h);

    for (int blk = 0; blk < NBLK; ++blk) {
        k_gslstm<<<BB / 16, 256, 0, stream>>>(
            h, Wgt + (size_t)blk * 512 * 128, bg + blk * 512,
            Rg + (size_t)blk * 16384, ln1g + blk * 128, ln1b + blk * 128,
            gng + blk * 128, gnb + blk * 128);
        k_ffn<<<MROWS / 128, 256, 0, stream>>>(
            h, W1t + (size_t)blk * 16384, W2t + (size_t)blk * 16384,
            ln2g + blk * 128, ln2b + blk * 128);
    }
    k_out<<<BB / 4, 256, 0, stream>>>(h, lnfg, lnfb, wout, bout, out);
}

// Round 6
// 683.817 us; speedup vs baseline: 3.4579x; 1.0503x over previous
//
#include <hip/hip_runtime.h>
#include <hip/hip_bf16.h>
#include <cstdint>
#include <cstddef>

#define EPS 1e-5f
#define BB 4096
#define TT 64
#define NBLK 2
#define MROWS (BB * TT)

typedef unsigned short ushort_t;
typedef __attribute__((ext_vector_type(8))) short short8;
typedef __attribute__((ext_vector_type(4))) float floatx4;

__device__ __forceinline__ ushort_t f2b(float f) {
    __hip_bfloat16 h = __float2bfloat16(f);
    return *reinterpret_cast<ushort_t*>(&h);
}
__device__ __forceinline__ float tanh_fast(float z) {
    return 1.f - 2.f / (__expf(2.f * z) + 1.f);
}
// LDS-only barrier. MUST be a single asm statement: llvm.amdgcn.s.barrier is
// IntrNoMem, so a separate builtin call lets the optimizer hoist LDS loads
// between the waitcnt and the barrier (round-5 race). One asm with a memory
// clobber pins all memory ops on both sides. Omits vmcnt drain on purpose:
// global buffers are wg-exclusive, so global loads/stores may float across.
__device__ __forceinline__ void lds_barrier() {
    asm volatile("s_waitcnt lgkmcnt(0)\n\ts_barrier" ::: "memory");
}

// ---------------- weight convert+transpose: dst[n][k] = bf16(src[k][n]) ----------------
__global__ __launch_bounds__(256) void k_cvtw(const float* __restrict__ src,
                                              ushort_t* __restrict__ dst, int N) {
    int idx = blockIdx.x * 256 + threadIdx.x;  // over N*128 (dst order)
    int n = idx >> 7, k = idx & 127;
    dst[idx] = f2b(src[(size_t)k * N + n]);
}

// ---------------- fused [embed +] gate-GEMM + sLSTM scan + GroupNorm + residual --------
// grid = BB/16 = 256 wgs, 256 thr (4 waves). Each wg owns 16 batches for all T.
// Wave = gate. Wg/R B-frags static in registers (round-4 proven shape).
// EMBED: h_in computed inline from x @ w_in + b_in (blk 0) instead of reading h.
template <bool EMBED>
__global__ __launch_bounds__(256, 1) void k_gslstm(
    float* __restrict__ h, const float* __restrict__ x,
    const float* __restrict__ w_in, const float* __restrict__ b_in,
    const ushort_t* __restrict__ Wgt, const float* __restrict__ bg,
    const float* __restrict__ Rg,
    const float* __restrict__ ln1g, const float* __restrict__ ln1b,
    const float* __restrict__ gng, const float* __restrict__ gnb) {
    __shared__ ushort_t Afrag[16][136];  // LN1(h_in) bf16, [m][k]
    __shared__ ushort_t Hlds[16][136];   // h_prev bf16, [m][k]
    __shared__ float Xbuf[16][516];      // gate preacts fp32, [b][g*128+d]

    int tid = threadIdx.x;
    int lane = tid & 63;
    int gate = tid >> 6;       // wave index = gate
    int q = lane >> 4, ml = lane & 15;
    int bo = tid >> 4;         // local batch (phase A/C ownership)
    int dl = tid & 15;         // d-octet: d = dl*8 .. dl*8+7
    int b0 = blockIdx.x * 16;

    // ---- static setup ----
    short8 WB[4][8];  // [k-slice][n-slice] of Wg for this gate
#pragma unroll
    for (int ks = 0; ks < 4; ++ks)
#pragma unroll
        for (int s = 0; s < 8; ++s)
            WB[ks][s] = *(const short8*)(Wgt +
                ((size_t)(gate * 128 + s * 16 + ml) * 128 + ks * 32 + q * 8));
    float biasv[8];
#pragma unroll
    for (int s = 0; s < 8; ++s) biasv[s] = bg[gate * 128 + s * 16 + ml];
    short8 RB[4][2];  // [head][n-slice], K=32
#pragma unroll
    for (int hh = 0; hh < 4; ++hh)
#pragma unroll
        for (int sr = 0; sr < 2; ++sr) {
            ushort_t tmp[8];
#pragma unroll
            for (int jj = 0; jj < 8; ++jj)
                tmp[jj] = f2b(Rg[((size_t)(gate * 4 + hh) * 32 + q * 8 + jj) * 32 +
                               sr * 16 + ml]);
            RB[hh][sr] = *(const short8*)tmp;
        }
    float lng_[8], lnb_[8], gng_[8], gnb_[8];
#pragma unroll
    for (int jj = 0; jj < 8; ++jj) {
        lng_[jj] = ln1g[dl * 8 + jj];
        lnb_[jj] = ln1b[dl * 8 + jj];
        gng_[jj] = gng[dl * 8 + jj];
        gnb_[jj] = gnb[dl * 8 + jj];
    }
    float we0[8], we1[8], we2[8], be[8];
    if (EMBED) {
#pragma unroll
        for (int jj = 0; jj < 8; ++jj) {
            we0[jj] = w_in[0 * 128 + dl * 8 + jj];
            we1[jj] = w_in[1 * 128 + dl * 8 + jj];
            we2[jj] = w_in[2 * 128 + dl * 8 + jj];
            be[jj] = b_in[dl * 8 + jj];
        }
    }
    float cst[8], nst[8], mst[8];
#pragma unroll
    for (int jj = 0; jj < 8; ++jj) { cst[jj] = 0.f; nst[jj] = 0.f; mst[jj] = 0.f; }

    for (int i = tid; i < 16 * 136; i += 256) ((ushort_t*)Hlds)[i] = 0;

    float cur0 = 0.f, cur1 = 0.f, cur2 = 0.f;
    float hin[8];
    if (EMBED) {
        const float* xp = x + (size_t)(b0 + bo) * TT * 3;
        cur0 = xp[0]; cur1 = xp[1]; cur2 = xp[2];
    } else {
        const float* p = h + ((size_t)(b0 + bo) * TT) * 128 + dl * 8;
        float4 v0 = *(const float4*)p;
        float4 v1 = *(const float4*)(p + 4);
        hin[0] = v0.x; hin[1] = v0.y; hin[2] = v0.z; hin[3] = v0.w;
        hin[4] = v1.x; hin[5] = v1.y; hin[6] = v1.z; hin[7] = v1.w;
    }
    lds_barrier();

    for (int t = 0; t < TT; ++t) {
        // ---- phase A: h_in + inline LN1 stats + Afrag stage + prefetch t+1 ----
        if (EMBED) {
#pragma unroll
            for (int jj = 0; jj < 8; ++jj)
                hin[jj] = cur0 * we0[jj] + cur1 * we1[jj] + cur2 * we2[jj] + be[jj];
        }
        float s = 0.f, ss = 0.f;
#pragma unroll
        for (int jj = 0; jj < 8; ++jj) { s += hin[jj]; ss += hin[jj] * hin[jj]; }
#pragma unroll
        for (int off = 1; off < 16; off <<= 1) {
            s += __shfl_xor(s, off);
            ss += __shfl_xor(ss, off);
        }
        float mu = s * (1.f / 128.f);
        float rstd = rsqrtf(ss * (1.f / 128.f) - mu * mu + EPS);
        {
            ushort_t ab[8];
#pragma unroll
            for (int jj = 0; jj < 8; ++jj)
                ab[jj] = f2b((hin[jj] - mu) * rstd * lng_[jj] + lnb_[jj]);
            *(short8*)&Afrag[bo][dl * 8] = *(const short8*)ab;
        }
        float hin2[8];
#pragma unroll
        for (int jj = 0; jj < 8; ++jj) hin2[jj] = 0.f;
        float nx0 = 0.f, nx1 = 0.f, nx2 = 0.f;
        if (t + 1 < TT) {
            if (EMBED) {
                const float* xp = x + ((size_t)(b0 + bo) * TT + t + 1) * 3;
                nx0 = xp[0]; nx1 = xp[1]; nx2 = xp[2];
            } else {
                const float* p = h + ((size_t)(b0 + bo) * TT + t + 1) * 128 + dl * 8;
                float4 v0 = *(const float4*)p;
                float4 v1 = *(const float4*)(p + 4);
                hin2[0] = v0.x; hin2[1] = v0.y; hin2[2] = v0.z; hin2[3] = v0.w;
                hin2[4] = v1.x; hin2[5] = v1.y; hin2[6] = v1.z; hin2[7] = v1.w;
            }
        }
        lds_barrier();  // b1: Afrag + Hlds(prev C) visible; Xbuf(prev) consumed

        // ---- phase B: MFMA xg + r + bias ----
        short8 af[4], hf[4];
#pragma unroll
        for (int ks = 0; ks < 4; ++ks)
            af[ks] = *(const short8*)&Afrag[ml][ks * 32 + q * 8];
#pragma unroll
        for (int hh = 0; hh < 4; ++hh)
            hf[hh] = *(const short8*)&Hlds[ml][hh * 32 + q * 8];
        floatx4 acc[8];
#pragma unroll
        for (int s8 = 0; s8 < 8; ++s8) {
            float b = biasv[s8];
            acc[s8] = (floatx4){b, b, b, b};
        }
#pragma unroll
        for (int ks = 0; ks < 4; ++ks)
#pragma unroll
            for (int s8 = 0; s8 < 8; ++s8)
                acc[s8] = __builtin_amdgcn_mfma_f32_16x16x32_bf16(
                    af[ks], WB[ks][s8], acc[s8], 0, 0, 0);
#pragma unroll
        for (int hh = 0; hh < 4; ++hh)
#pragma unroll
            for (int sr = 0; sr < 2; ++sr)
                acc[hh * 2 + sr] = __builtin_amdgcn_mfma_f32_16x16x32_bf16(
                    hf[hh], RB[hh][sr], acc[hh * 2 + sr], 0, 0, 0);
#pragma unroll
        for (int s8 = 0; s8 < 8; ++s8)
#pragma unroll
            for (int r = 0; r < 4; ++r)
                Xbuf[q * 4 + r][gate * 128 + s8 * 16 + ml] = acc[s8][r];
        lds_barrier();  // b2: Xbuf ready

        // ---- phase C: nonlinearities + GN + residual ----
        float it[8], ft[8], zt[8], ot[8];
        {
            float4 a0 = *(const float4*)&Xbuf[bo][0 * 128 + dl * 8];
            float4 a1 = *(const float4*)&Xbuf[bo][0 * 128 + dl * 8 + 4];
            it[0] = a0.x; it[1] = a0.y; it[2] = a0.z; it[3] = a0.w;
            it[4] = a1.x; it[5] = a1.y; it[6] = a1.z; it[7] = a1.w;
            float4 f0 = *(const float4*)&Xbuf[bo][1 * 128 + dl * 8];
            float4 f1 = *(const float4*)&Xbuf[bo][1 * 128 + dl * 8 + 4];
            ft[0] = f0.x; ft[1] = f0.y; ft[2] = f0.z; ft[3] = f0.w;
            ft[4] = f1.x; ft[5] = f1.y; ft[6] = f1.z; ft[7] = f1.w;
            float4 z0 = *(const float4*)&Xbuf[bo][2 * 128 + dl * 8];
            float4 z1 = *(const float4*)&Xbuf[bo][2 * 128 + dl * 8 + 4];
            zt[0] = z0.x; zt[1] = z0.y; zt[2] = z0.z; zt[3] = z0.w;
            zt[4] = z1.x; zt[5] = z1.y; zt[6] = z1.z; zt[7] = z1.w;
            float4 o0 = *(const float4*)&Xbuf[bo][3 * 128 + dl * 8];
            float4 o1 = *(const float4*)&Xbuf[bo][3 * 128 + dl * 8 + 4];
            ot[0] = o0.x; ot[1] = o0.y; ot[2] = o0.z; ot[3] = o0.w;
            ot[4] = o1.x; ot[5] = o1.y; ot[6] = o1.z; ot[7] = o1.w;
        }
        float hv[8];
#pragma unroll
        for (int jj = 0; jj < 8; ++jj) {
            float mn = fmaxf(ft[jj] + mst[jj], it[jj]);
            float iv = __expf(it[jj] - mn);
            float fv = __expf(ft[jj] + mst[jj] - mn);
            float cn = fv * cst[jj] + iv * tanh_fast(zt[jj]);
            float nn = fv * nst[jj] + iv;
            hv[jj] = cn / (nn * (1.f + __expf(-ot[jj])));
            cst[jj] = cn; nst[jj] = nn; mst[jj] = mn;
        }
        // GroupNorm over head (32 dims): local 8 + shfl over dl bits 0-1
        float s2 = 0.f, q2 = 0.f;
#pragma unroll
        for (int jj = 0; jj < 8; ++jj) { s2 += hv[jj]; q2 += hv[jj] * hv[jj]; }
        s2 += __shfl_xor(s2, 1); q2 += __shfl_xor(q2, 1);
        s2 += __shfl_xor(s2, 2); q2 += __shfl_xor(q2, 2);
        float mu2 = s2 * (1.f / 32.f);
        float rstd2 = rsqrtf(q2 * (1.f / 32.f) - mu2 * mu2 + EPS);
        {
            float o[8];
#pragma unroll
            for (int jj = 0; jj < 8; ++jj)
                o[jj] = hin[jj] + (hv[jj] - mu2) * rstd2 * gng_[jj] + gnb_[jj];
            float* po = h + ((size_t)(b0 + bo) * TT + t) * 128 + dl * 8;
            *(float4*)po = make_float4(o[0], o[1], o[2], o[3]);
            *(float4*)(po + 4) = make_float4(o[4], o[5], o[6], o[7]);
            ushort_t hb[8];
#pragma unroll
            for (int jj = 0; jj < 8; ++jj) hb[jj] = f2b(hv[jj]);
            *(short8*)&Hlds[bo][dl * 8] = *(const short8*)hb;
        }
        if (EMBED) { cur0 = nx0; cur1 = nx1; cur2 = nx2; }
        else {
#pragma unroll
            for (int jj = 0; jj < 8; ++jj) hin[jj] = hin2[jj];
        }
        // no barrier here: next phase A writes only Afrag (disjoint); b1 orders
        // Hlds writes + Xbuf reads before next phase B.
    }
}

// ---------------- fused FFN: h += gelu(LN2(h) @ W1) @ W2, stats inline ----------------
// M=128 tiles (round-4 shape), lightweight barriers, weight loads hoisted.
__global__ __launch_bounds__(256, 2) void k_ffn(
    float* __restrict__ h, const ushort_t* __restrict__ W1t,
    const ushort_t* __restrict__ W2t,
    const float* __restrict__ lng, const float* __restrict__ lnb) {
    __shared__ ushort_t As[128][136];
    __shared__ ushort_t T1[128][136];
    int tid = threadIdx.x;
    int lane = tid & 63, wave = tid >> 6;
    int q = lane >> 4, ml = lane & 15;
    int wm = (wave & 1) * 64, wn = (wave >> 1) * 64;
    size_t row0 = (size_t)blockIdx.x * 128;

    // hoist W1 fragments (latency hidden under stats phase)
    short8 W1B[4][4];  // [jn][ks]
#pragma unroll
    for (int jn = 0; jn < 4; ++jn)
#pragma unroll
        for (int ks = 0; ks < 4; ++ks)
            W1B[jn][ks] = *(const short8*)(W1t +
                ((size_t)(wn + jn * 16 + ml) * 128 + ks * 32 + q * 8));

    // inline LN2 stats: 2 threads per row
    int r = tid >> 1, hf = tid & 1;
    const float* hrow = h + (row0 + r) * 128 + hf * 64;
    float s = 0.f, ss = 0.f;
#pragma unroll
    for (int k = 0; k < 16; ++k) {
        float4 v = ((const float4*)hrow)[k];
        s += v.x + v.y + v.z + v.w;
        ss += v.x * v.x + v.y * v.y + v.z * v.z + v.w * v.w;
    }
    s += __shfl_xor(s, 1);
    ss += __shfl_xor(ss, 1);
    float mu = s * (1.f / 128.f);
    float rstd = rsqrtf(ss * (1.f / 128.f) - mu * mu + EPS);
#pragma unroll
    for (int kk = 0; kk < 8; ++kk) {
        float4 a = ((const float4*)hrow)[2 * kk];
        float4 b = ((const float4*)hrow)[2 * kk + 1];
        float4 g0 = *(const float4*)(lng + hf * 64 + kk * 8);
        float4 g1 = *(const float4*)(lng + hf * 64 + kk * 8 + 4);
        float4 b0 = *(const float4*)(lnb + hf * 64 + kk * 8);
        float4 b1 = *(const float4*)(lnb + hf * 64 + kk * 8 + 4);
        ushort_t p[8];
        p[0] = f2b((a.x - mu) * rstd * g0.x + b0.x);
        p[1] = f2b((a.y - mu) * rstd * g0.y + b0.y);
        p[2] = f2b((a.z - mu) * rstd * g0.z + b0.z);
        p[3] = f2b((a.w - mu) * rstd * g0.w + b0.w);
        p[4] = f2b((b.x - mu) * rstd * g1.x + b1.x);
        p[5] = f2b((b.y - mu) * rstd * g1.y + b1.y);
        p[6] = f2b((b.z - mu) * rstd * g1.z + b1.z);
        p[7] = f2b((b.w - mu) * rstd * g1.w + b1.w);
        *(short8*)&As[r][hf * 64 + kk * 8] = *(const short8*)p;
    }
    lds_barrier();

    // MFMA1: t1 = gelu(As @ W1)
    floatx4 acc1[4][4];
#pragma unroll
    for (int i = 0; i < 4; ++i)
#pragma unroll
        for (int j = 0; j < 4; ++j) acc1[i][j] = (floatx4)0.f;
#pragma unroll
    for (int ks = 0; ks < 4; ++ks) {
        short8 af[4];
#pragma unroll
        for (int im = 0; im < 4; ++im)
            af[im] = *(const short8*)&As[wm + im * 16 + ml][ks * 32 + q * 8];
#pragma unroll
        for (int im = 0; im < 4; ++im)
#pragma unroll
            for (int jn = 0; jn < 4; ++jn)
                acc1[im][jn] = __builtin_amdgcn_mfma_f32_16x16x32_bf16(
                    af[im], W1B[jn][ks], acc1[im][jn], 0, 0, 0);
    }
#pragma unroll
    for (int im = 0; im < 4; ++im)
#pragma unroll
        for (int jn = 0; jn < 4; ++jn)
#pragma unroll
            for (int rr = 0; rr < 4; ++rr) {
                float v = acc1[im][jn][rr];
                float u = 0.7978845608028654f * (v + 0.044715f * v * v * v);
                float gv = 0.5f * v * (1.f + tanh_fast(u));
                T1[wm + im * 16 + q * 4 + rr][wn + jn * 16 + ml] = f2b(gv);
            }
    // prefetch W2 fragments before the barrier (overlaps barrier/drain)
    short8 W2B[4][4];
#pragma unroll
    for (int jn = 0; jn < 4; ++jn)
#pragma unroll
        for (int ks = 0; ks < 4; ++ks)
            W2B[jn][ks] = *(const short8*)(W2t +
                ((size_t)(wn + jn * 16 + ml) * 128 + ks * 32 + q * 8));
    lds_barrier();

    // MFMA2: h += T1 @ W2
    floatx4 acc2[4][4];
#pragma unroll
    for (int i = 0; i < 4; ++i)
#pragma unroll
        for (int j = 0; j < 4; ++j) acc2[i][j] = (floatx4)0.f;
#pragma unroll
    for (int ks = 0; ks < 4; ++ks) {
        short8 af[4];
#pragma unroll
        for (int im = 0; im < 4; ++im)
            af[im] = *(const short8*)&T1[wm + im * 16 + ml][ks * 32 + q * 8];
#pragma unroll
        for (int im = 0; im < 4; ++im)
#pragma unroll
            for (int jn = 0; jn < 4; ++jn)
                acc2[im][jn] = __builtin_amdgcn_mfma_f32_16x16x32_bf16(
                    af[im], W2B[jn][ks], acc2[im][jn], 0, 0, 0);
    }
#pragma unroll
    for (int im = 0; im < 4; ++im)
#pragma unroll
        for (int jn = 0; jn < 4; ++jn)
#pragma unroll
            for (int rr = 0; rr < 4; ++rr) {
                size_t rw = row0 + wm + im * 16 + q * 4 + rr;
                int cc = wn + jn * 16 + ml;
                h[rw * 128 + cc] += acc2[im][jn][rr];
            }
}

// ---------------- final LN (t=T-1 only) + matvec ----------------
__global__ __launch_bounds__(256) void k_out(const float* __restrict__ h,
                                             const float* __restrict__ lnfg,
                                             const float* __restrict__ lnfb,
                                             const float* __restrict__ w_out,
                                             const float* __restrict__ b_out,
                                             float* __restrict__ out) {
    int b = blockIdx.x * 4 + (threadIdx.x >> 6);
    int l = threadIdx.x & 63;
    const float* hr = h + ((size_t)b * TT + (TT - 1)) * 128;
    float2 v = *(const float2*)(hr + l * 2);
    float s = v.x + v.y, ss = v.x * v.x + v.y * v.y;
#pragma unroll
    for (int off = 1; off < 64; off <<= 1) {
        s += __shfl_xor(s, off);
        ss += __shfl_xor(ss, off);
    }
    float mu_ = s * (1.f / 128.f);
    float rstd = rsqrtf(ss * (1.f / 128.f) - mu_ * mu_ + EPS);
    float2 g = *(const float2*)(lnfg + l * 2);
    float2 bb = *(const float2*)(lnfb + l * 2);
    float2 w = *(const float2*)(w_out + l * 2);
    float dot = ((v.x - mu_) * rstd * g.x + bb.x) * w.x +
                ((v.y - mu_) * rstd * g.y + bb.y) * w.y;
#pragma unroll
    for (int off = 1; off < 64; off <<= 1) dot += __shfl_xor(dot, off);
    if (l == 0) out[b] = dot + b_out[0];
}

extern "C" void kernel_launch(void* const* d_in, const int* in_sizes, int n_in,
                              void* d_out, int out_size, void* d_ws, size_t ws_size,
                              hipStream_t stream) {
    const float* x    = (const float*)d_in[0];
    const float* w_in = (const float*)d_in[1];
    const float* b_in = (const float*)d_in[2];
    const float* ln1g = (const float*)d_in[3];
    const float* ln1b = (const float*)d_in[4];
    const float* Wg   = (const float*)d_in[5];
    const float* bg   = (const float*)d_in[6];
    const float* Rg   = (const float*)d_in[7];
    const float* gng  = (const float*)d_in[8];
    const float* gnb  = (const float*)d_in[9];
    const float* ln2g = (const float*)d_in[10];
    const float* ln2b = (const float*)d_in[11];
    const float* W1   = (const float*)d_in[12];
    const float* W2   = (const float*)d_in[13];
    const float* lnfg = (const float*)d_in[14];
    const float* lnfb = (const float*)d_in[15];
    const float* wout = (const float*)d_in[16];
    const float* bout = (const float*)d_in[17];
    float* out = (float*)d_out;

    // ws: h fp32 (134.2 MB) | Wgt bf16 [blk][512][128] | W1t | W2t  (~134.6 MB)
    float* h = (float*)d_ws;
    ushort_t* Wgt = (ushort_t*)(h + (size_t)MROWS * 128);
    ushort_t* W1t = Wgt + 2 * 512 * 128;
    ushort_t* W2t = W1t + 2 * 128 * 128;

    for (int blk = 0; blk < NBLK; ++blk) {
        k_cvtw<<<512 * 128 / 256, 256, 0, stream>>>(Wg + (size_t)blk * 128 * 512,
                                                    Wgt + (size_t)blk * 512 * 128, 512);
        k_cvtw<<<128 * 128 / 256, 256, 0, stream>>>(W1 + (size_t)blk * 16384,
                                                    W1t + (size_t)blk * 16384, 128);
        k_cvtw<<<128 * 128 / 256, 256, 0, stream>>>(W2 + (size_t)blk * 16384,
                                                    W2t + (size_t)blk * 16384, 128);
    }

    // blk 0: embed fused into the scan (reads x, not h)
    k_gslstm<true><<<BB / 16, 256, 0, stream>>>(
        h, x, w_in, b_in, Wgt, bg, Rg, ln1g, ln1b, gng, gnb);
    k_ffn<<<MROWS / 128, 256, 0, stream>>>(h, W1t, W2t, ln2g, ln2b);
    // blk 1
    k_gslstm<false><<<BB / 16, 256, 0, stream>>>(
        h, nullptr, nullptr, nullptr, Wgt + (size_t)512 * 128, bg + 512,
        Rg + (size_t)16384, ln1g + 128, ln1b + 128, gng + 128, gnb + 128);
    k_ffn<<<MROWS / 128, 256, 0, stream>>>(h, W1t + 16384, W2t + 16384,
                                           ln2g + 128, ln2b + 128);
    k_out<<<BB / 4, 256, 0, stream>>>(h, lnfg, lnfb, wout, bout, out);
}

// Round 7
// 599.509 us; speedup vs baseline: 3.9441x; 1.1406x over previous
//
#include <hip/hip_runtime.h>
#include <hip/hip_bf16.h>
#include <cstdint>
#include <cstddef>

#define EPS 1e-5f
#define BB 4096
#define TT 64
#define NBLK 2
#define MROWS (BB * TT)

typedef unsigned short ushort_t;
typedef __attribute__((ext_vector_type(8))) short short8;
typedef __attribute__((ext_vector_type(4))) float floatx4;

__device__ __forceinline__ ushort_t f2b(float f) {
    __hip_bfloat16 h = __float2bfloat16(f);
    return *reinterpret_cast<ushort_t*>(&h);
}
__device__ __forceinline__ float tanh_fast(float z) {
    return 1.f - 2.f / (__expf(2.f * z) + 1.f);
}
// LDS-only barrier, single asm statement (round-5 lesson: separate
// builtin_amdgcn_s_barrier is IntrNoMem and lets LDS ops hoist past the
// waitcnt). Omits vmcnt drain: global buffers are wg-exclusive.
__device__ __forceinline__ void lds_barrier() {
    asm volatile("s_waitcnt lgkmcnt(0)\n\ts_barrier" ::: "memory");
}

// ---------------- all weight converts in one launch ----------------
// Wgt[blk][n<512][k<128] <- Wg[blk][k][n]; W1t/W2t[blk][n<128][k<128]
__global__ __launch_bounds__(256) void k_cvtall(
    const float* __restrict__ Wg, const float* __restrict__ W1,
    const float* __restrict__ W2, ushort_t* __restrict__ Wgt,
    ushort_t* __restrict__ W1t, ushort_t* __restrict__ W2t) {
    int idx = blockIdx.x * 256 + threadIdx.x;
    if (idx < 2 * 512 * 128) {
        int blk = idx >> 16, r = idx & 65535;
        int n = r >> 7, k = r & 127;
        Wgt[idx] = f2b(Wg[(size_t)blk * 65536 + k * 512 + n]);
    } else if (idx < 2 * 512 * 128 + 2 * 128 * 128) {
        int i2 = idx - 2 * 512 * 128;
        int blk = i2 >> 14, r = i2 & 16383;
        int n = r >> 7, k = r & 127;
        W1t[i2] = f2b(W1[(size_t)blk * 16384 + k * 128 + n]);
    } else {
        int i2 = idx - (2 * 512 * 128 + 2 * 128 * 128);
        int blk = i2 >> 14, r = i2 & 16383;
        int n = r >> 7, k = r & 127;
        W2t[i2] = f2b(W2[(size_t)blk * 16384 + k * 128 + n]);
    }
}

// ---------------- fused [embed +] gate-GEMM + sLSTM scan + GroupNorm + residual --------
// grid = BB/16 = 256 wgs, 512 thr (8 waves -> 2 waves/SIMD). Wg owns 16 batches, all T.
// Wave = (gate, half): gate = wave>>1, N-columns half*64..+64 of that gate.
// Per wave: WB[4][4] (64 VGPR), RB[2][2] (2 heads), 20 MFMAs/step.
template <bool EMBED>
__global__ __launch_bounds__(512, 2) void k_gslstm(
    float* __restrict__ h, const float* __restrict__ x,
    const float* __restrict__ w_in, const float* __restrict__ b_in,
    const ushort_t* __restrict__ Wgt, const float* __restrict__ bg,
    const float* __restrict__ Rg,
    const float* __restrict__ ln1g, const float* __restrict__ ln1b,
    const float* __restrict__ gng, const float* __restrict__ gnb) {
    __shared__ ushort_t Afrag[16][136];  // LN1(h_in) bf16, [m][k]
    __shared__ ushort_t Hlds[16][136];   // h_prev bf16, [m][k]
    __shared__ float Xbuf[16][516];      // gate preacts fp32, [b][g*128+d]

    int tid = threadIdx.x;        // 0..511
    int lane = tid & 63;
    int wave = tid >> 6;          // 0..7
    int gate = wave >> 1;
    int half = wave & 1;
    int q = lane >> 4, ml = lane & 15;
    int bo = tid >> 5;            // local batch 0..15 (phase A/C ownership)
    int dl = tid & 31;            // dims dl*4 .. dl*4+3
    int b0 = blockIdx.x * 16;

    // ---- static setup ----
    short8 WB[4][4];  // [k-slice][n-slice] of this wave's 64 columns
#pragma unroll
    for (int ks = 0; ks < 4; ++ks)
#pragma unroll
        for (int s = 0; s < 4; ++s)
            WB[ks][s] = *(const short8*)(Wgt +
                ((size_t)(gate * 128 + half * 64 + s * 16 + ml) * 128 + ks * 32 + q * 8));
    float biasv[4];
#pragma unroll
    for (int s = 0; s < 4; ++s) biasv[s] = bg[gate * 128 + half * 64 + s * 16 + ml];
    // R: heads 2*half+hb (hb<2), n-slice sr<2 -> accumulates into acc[hb*2+sr]
    short8 RB[2][2];
#pragma unroll
    for (int hb = 0; hb < 2; ++hb)
#pragma unroll
        for (int sr = 0; sr < 2; ++sr) {
            ushort_t tmp[8];
#pragma unroll
            for (int jj = 0; jj < 8; ++jj)
                tmp[jj] = f2b(Rg[((size_t)(gate * 4 + 2 * half + hb) * 32 + q * 8 + jj) * 32 +
                               sr * 16 + ml]);
            RB[hb][sr] = *(const short8*)tmp;
        }
    float lng_[4], lnb_[4], gng_[4], gnb_[4];
#pragma unroll
    for (int jj = 0; jj < 4; ++jj) {
        lng_[jj] = ln1g[dl * 4 + jj];
        lnb_[jj] = ln1b[dl * 4 + jj];
        gng_[jj] = gng[dl * 4 + jj];
        gnb_[jj] = gnb[dl * 4 + jj];
    }
    float we0[4], we1[4], we2[4], be[4];
    if (EMBED) {
#pragma unroll
        for (int jj = 0; jj < 4; ++jj) {
            we0[jj] = w_in[0 * 128 + dl * 4 + jj];
            we1[jj] = w_in[1 * 128 + dl * 4 + jj];
            we2[jj] = w_in[2 * 128 + dl * 4 + jj];
            be[jj] = b_in[dl * 4 + jj];
        }
    }
    float cst[4], nst[4], mst[4];
#pragma unroll
    for (int jj = 0; jj < 4; ++jj) { cst[jj] = 0.f; nst[jj] = 0.f; mst[jj] = 0.f; }

    for (int i = tid; i < 16 * 136; i += 512) ((ushort_t*)Hlds)[i] = 0;

    float cur0 = 0.f, cur1 = 0.f, cur2 = 0.f;
    float hin[4];
    if (EMBED) {
        const float* xp = x + (size_t)(b0 + bo) * TT * 3;
        cur0 = xp[0]; cur1 = xp[1]; cur2 = xp[2];
    } else {
        float4 v = *(const float4*)(h + ((size_t)(b0 + bo) * TT) * 128 + dl * 4);
        hin[0] = v.x; hin[1] = v.y; hin[2] = v.z; hin[3] = v.w;
    }
    lds_barrier();

    for (int t = 0; t < TT; ++t) {
        // ---- phase A: h_in + inline LN1 stats + Afrag stage + prefetch t+1 ----
        if (EMBED) {
#pragma unroll
            for (int jj = 0; jj < 4; ++jj)
                hin[jj] = cur0 * we0[jj] + cur1 * we1[jj] + cur2 * we2[jj] + be[jj];
        }
        float s = 0.f, ss = 0.f;
#pragma unroll
        for (int jj = 0; jj < 4; ++jj) { s += hin[jj]; ss += hin[jj] * hin[jj]; }
#pragma unroll
        for (int off = 1; off < 32; off <<= 1) {
            s += __shfl_xor(s, off);
            ss += __shfl_xor(ss, off);
        }
        float mu = s * (1.f / 128.f);
        float rstd = rsqrtf(ss * (1.f / 128.f) - mu * mu + EPS);
        {
            ushort_t ab[4];
#pragma unroll
            for (int jj = 0; jj < 4; ++jj)
                ab[jj] = f2b((hin[jj] - mu) * rstd * lng_[jj] + lnb_[jj]);
            *(uint2*)&Afrag[bo][dl * 4] = *(const uint2*)ab;
        }
        float hin2[4] = {0.f, 0.f, 0.f, 0.f};
        float nx0 = 0.f, nx1 = 0.f, nx2 = 0.f;
        if (t + 1 < TT) {
            if (EMBED) {
                const float* xp = x + ((size_t)(b0 + bo) * TT + t + 1) * 3;
                nx0 = xp[0]; nx1 = xp[1]; nx2 = xp[2];
            } else {
                float4 v = *(const float4*)(h + ((size_t)(b0 + bo) * TT + t + 1) * 128 + dl * 4);
                hin2[0] = v.x; hin2[1] = v.y; hin2[2] = v.z; hin2[3] = v.w;
            }
        }
        lds_barrier();  // b1: Afrag + Hlds(prev C) visible; Xbuf(prev) consumed

        // ---- phase B: MFMA xg + r + bias ----
        short8 af[4], hf[2];
#pragma unroll
        for (int ks = 0; ks < 4; ++ks)
            af[ks] = *(const short8*)&Afrag[ml][ks * 32 + q * 8];
#pragma unroll
        for (int hb = 0; hb < 2; ++hb)
            hf[hb] = *(const short8*)&Hlds[ml][(2 * half + hb) * 32 + q * 8];
        floatx4 acc[4];
#pragma unroll
        for (int s4 = 0; s4 < 4; ++s4) {
            float b = biasv[s4];
            acc[s4] = (floatx4){b, b, b, b};
        }
#pragma unroll
        for (int ks = 0; ks < 4; ++ks)
#pragma unroll
            for (int s4 = 0; s4 < 4; ++s4)
                acc[s4] = __builtin_amdgcn_mfma_f32_16x16x32_bf16(
                    af[ks], WB[ks][s4], acc[s4], 0, 0, 0);
#pragma unroll
        for (int hb = 0; hb < 2; ++hb)
#pragma unroll
            for (int sr = 0; sr < 2; ++sr)
                acc[hb * 2 + sr] = __builtin_amdgcn_mfma_f32_16x16x32_bf16(
                    hf[hb], RB[hb][sr], acc[hb * 2 + sr], 0, 0, 0);
#pragma unroll
        for (int s4 = 0; s4 < 4; ++s4)
#pragma unroll
            for (int r = 0; r < 4; ++r)
                Xbuf[q * 4 + r][gate * 128 + half * 64 + s4 * 16 + ml] = acc[s4][r];
        lds_barrier();  // b2: Xbuf ready

        // ---- phase C: nonlinearities + GN + residual (4 dims/thread) ----
        float it[4], ft[4], zt[4], ot[4];
        {
            float4 a = *(const float4*)&Xbuf[bo][0 * 128 + dl * 4];
            it[0] = a.x; it[1] = a.y; it[2] = a.z; it[3] = a.w;
            float4 f = *(const float4*)&Xbuf[bo][1 * 128 + dl * 4];
            ft[0] = f.x; ft[1] = f.y; ft[2] = f.z; ft[3] = f.w;
            float4 z = *(const float4*)&Xbuf[bo][2 * 128 + dl * 4];
            zt[0] = z.x; zt[1] = z.y; zt[2] = z.z; zt[3] = z.w;
            float4 o = *(const float4*)&Xbuf[bo][3 * 128 + dl * 4];
            ot[0] = o.x; ot[1] = o.y; ot[2] = o.z; ot[3] = o.w;
        }
        float hv[4];
#pragma unroll
        for (int jj = 0; jj < 4; ++jj) {
            float mn = fmaxf(ft[jj] + mst[jj], it[jj]);
            float iv = __expf(it[jj] - mn);
            float fv = __expf(ft[jj] + mst[jj] - mn);
            float cn = fv * cst[jj] + iv * tanh_fast(zt[jj]);
            float nn = fv * nst[jj] + iv;
            hv[jj] = cn / (nn * (1.f + __expf(-ot[jj])));
            cst[jj] = cn; nst[jj] = nn; mst[jj] = mn;
        }
        // GroupNorm over head (32 dims): 4 local + shfl over dl bits 0-2
        float s2 = 0.f, q2 = 0.f;
#pragma unroll
        for (int jj = 0; jj < 4; ++jj) { s2 += hv[jj]; q2 += hv[jj] * hv[jj]; }
        s2 += __shfl_xor(s2, 1); q2 += __shfl_xor(q2, 1);
        s2 += __shfl_xor(s2, 2); q2 += __shfl_xor(q2, 2);
        s2 += __shfl_xor(s2, 4); q2 += __shfl_xor(q2, 4);
        float mu2 = s2 * (1.f / 32.f);
        float rstd2 = rsqrtf(q2 * (1.f / 32.f) - mu2 * mu2 + EPS);
        {
            float o[4];
#pragma unroll
            for (int jj = 0; jj < 4; ++jj)
                o[jj] = hin[jj] + (hv[jj] - mu2) * rstd2 * gng_[jj] + gnb_[jj];
            float* po = h + ((size_t)(b0 + bo) * TT + t) * 128 + dl * 4;
            *(float4*)po = make_float4(o[0], o[1], o[2], o[3]);
            ushort_t hb16[4];
#pragma unroll
            for (int jj = 0; jj < 4; ++jj) hb16[jj] = f2b(hv[jj]);
            *(uint2*)&Hlds[bo][dl * 4] = *(const uint2*)hb16;
        }
        if (EMBED) { cur0 = nx0; cur1 = nx1; cur2 = nx2; }
        else {
#pragma unroll
            for (int jj = 0; jj < 4; ++jj) hin[jj] = hin2[jj];
        }
        // no barrier: next phase A writes only Afrag (disjoint); b1 orders
        // Hlds writes + Xbuf reads before next phase B.
    }
}

// ---------------- fused FFN: h += gelu(LN2(h) @ W1) @ W2, stats inline ----------------
// M=64 tiles, 34.8 KB LDS -> 3 wgs/CU. Weight fragments hoisted.
__global__ __launch_bounds__(256, 3) void k_ffn(
    float* __restrict__ h, const ushort_t* __restrict__ W1t,
    const ushort_t* __restrict__ W2t,
    const float* __restrict__ lng, const float* __restrict__ lnb) {
    __shared__ ushort_t As[64][136];
    __shared__ ushort_t T1[64][136];
    int tid = threadIdx.x;
    int lane = tid & 63, wave = tid >> 6;
    int q = lane >> 4, ml = lane & 15;
    int wn = wave * 32;  // wave's 32-column slice
    size_t row0 = (size_t)blockIdx.x * 64;

    // hoist W1 fragments (latency hidden under stats)
    short8 W1B[2][4];
#pragma unroll
    for (int jn = 0; jn < 2; ++jn)
#pragma unroll
        for (int ks = 0; ks < 4; ++ks)
            W1B[jn][ks] = *(const short8*)(W1t +
                ((size_t)(wn + jn * 16 + ml) * 128 + ks * 32 + q * 8));

    // inline LN2 stats: 4 threads per row, 32 dims each
    int r = tid >> 2, qd = tid & 3;
    const float* hrow = h + (row0 + r) * 128 + qd * 32;
    float s = 0.f, ss = 0.f;
#pragma unroll
    for (int k = 0; k < 8; ++k) {
        float4 v = ((const float4*)hrow)[k];
        s += v.x + v.y + v.z + v.w;
        ss += v.x * v.x + v.y * v.y + v.z * v.z + v.w * v.w;
    }
    s += __shfl_xor(s, 1); ss += __shfl_xor(ss, 1);
    s += __shfl_xor(s, 2); ss += __shfl_xor(ss, 2);
    float mu = s * (1.f / 128.f);
    float rstd = rsqrtf(ss * (1.f / 128.f) - mu * mu + EPS);
#pragma unroll
    for (int kk = 0; kk < 4; ++kk) {
        float4 a = ((const float4*)hrow)[2 * kk];
        float4 b = ((const float4*)hrow)[2 * kk + 1];
        int c0 = qd * 32 + kk * 8;
        float4 g0 = *(const float4*)(lng + c0);
        float4 g1 = *(const float4*)(lng + c0 + 4);
        float4 b0 = *(const float4*)(lnb + c0);
        float4 b1 = *(const float4*)(lnb + c0 + 4);
        ushort_t p[8];
        p[0] = f2b((a.x - mu) * rstd * g0.x + b0.x);
        p[1] = f2b((a.y - mu) * rstd * g0.y + b0.y);
        p[2] = f2b((a.z - mu) * rstd * g0.z + b0.z);
        p[3] = f2b((a.w - mu) * rstd * g0.w + b0.w);
        p[4] = f2b((b.x - mu) * rstd * g1.x + b1.x);
        p[5] = f2b((b.y - mu) * rstd * g1.y + b1.y);
        p[6] = f2b((b.z - mu) * rstd * g1.z + b1.z);
        p[7] = f2b((b.w - mu) * rstd * g1.w + b1.w);
        *(short8*)&As[r][c0] = *(const short8*)p;
    }
    lds_barrier();

    // MFMA1: t1 = gelu(As @ W1)
    floatx4 acc[4][2];
#pragma unroll
    for (int i = 0; i < 4; ++i)
#pragma unroll
        for (int j = 0; j < 2; ++j) acc[i][j] = (floatx4)0.f;
#pragma unroll
    for (int ks = 0; ks < 4; ++ks) {
        short8 af[4];
#pragma unroll
        for (int im = 0; im < 4; ++im)
            af[im] = *(const short8*)&As[im * 16 + ml][ks * 32 + q * 8];
#pragma unroll
        for (int im = 0; im < 4; ++im)
#pragma unroll
            for (int jn = 0; jn < 2; ++jn)
                acc[im][jn] = __builtin_amdgcn_mfma_f32_16x16x32_bf16(
                    af[im], W1B[jn][ks], acc[im][jn], 0, 0, 0);
    }
#pragma unroll
    for (int im = 0; im < 4; ++im)
#pragma unroll
        for (int jn = 0; jn < 2; ++jn)
#pragma unroll
            for (int rr = 0; rr < 4; ++rr) {
                float v = acc[im][jn][rr];
                float u = 0.7978845608028654f * (v + 0.044715f * v * v * v);
                float gv = 0.5f * v * (1.f + tanh_fast(u));
                T1[im * 16 + q * 4 + rr][wn + jn * 16 + ml] = f2b(gv);
            }
    // prefetch W2 fragments before the barrier
    short8 W2B[2][4];
#pragma unroll
    for (int jn = 0; jn < 2; ++jn)
#pragma unroll
        for (int ks = 0; ks < 4; ++ks)
            W2B[jn][ks] = *(const short8*)(W2t +
                ((size_t)(wn + jn * 16 + ml) * 128 + ks * 32 + q * 8));
    lds_barrier();

    // MFMA2: h += T1 @ W2
#pragma unroll
    for (int i = 0; i < 4; ++i)
#pragma unroll
        for (int j = 0; j < 2; ++j) acc[i][j] = (floatx4)0.f;
#pragma unroll
    for (int ks = 0; ks < 4; ++ks) {
        short8 af[4];
#pragma unroll
        for (int im = 0; im < 4; ++im)
            af[im] = *(const short8*)&T1[im * 16 + ml][ks * 32 + q * 8];
#pragma unroll
        for (int im = 0; im < 4; ++im)
#pragma unroll
            for (int jn = 0; jn < 2; ++jn)
                acc[im][jn] = __builtin_amdgcn_mfma_f32_16x16x32_bf16(
                    af[im], W2B[jn][ks], acc[im][jn], 0, 0, 0);
    }
#pragma unroll
    for (int im = 0; im < 4; ++im)
#pragma unroll
        for (int jn = 0; jn < 2; ++jn)
#pragma unroll
            for (int rr = 0; rr < 4; ++rr) {
                size_t rw = row0 + im * 16 + q * 4 + rr;
                int cc = wn + jn * 16 + ml;
                h[rw * 128 + cc] += acc[im][jn][rr];
            }
}

// ---------------- final LN (t=T-1 only) + matvec ----------------
__global__ __launch_bounds__(256) void k_out(const float* __restrict__ h,
                                             const float* __restrict__ lnfg,
                                             const float* __restrict__ lnfb,
                                             const float* __restrict__ w_out,
                                             const float* __restrict__ b_out,
                                             float* __restrict__ out) {
    int b = blockIdx.x * 4 + (threadIdx.x >> 6);
    int l = threadIdx.x & 63;
    const float* hr = h + ((size_t)b * TT + (TT - 1)) * 128;
    float2 v = *(const float2*)(hr + l * 2);
    float s = v.x + v.y, ss = v.x * v.x + v.y * v.y;
#pragma unroll
    for (int off = 1; off < 64; off <<= 1) {
        s += __shfl_xor(s, off);
        ss += __shfl_xor(ss, off);
    }
    float mu_ = s * (1.f / 128.f);
    float rstd = rsqrtf(ss * (1.f / 128.f) - mu_ * mu_ + EPS);
    float2 g = *(const float2*)(lnfg + l * 2);
    float2 bb = *(const float2*)(lnfb + l * 2);
    float2 w = *(const float2*)(w_out + l * 2);
    float dot = ((v.x - mu_) * rstd * g.x + bb.x) * w.x +
                ((v.y - mu_) * rstd * g.y + bb.y) * w.y;
#pragma unroll
    for (int off = 1; off < 64; off <<= 1) dot += __shfl_xor(dot, off);
    if (l == 0) out[b] = dot + b_out[0];
}

extern "C" void kernel_launch(void* const* d_in, const int* in_sizes, int n_in,
                              void* d_out, int out_size, void* d_ws, size_t ws_size,
                              hipStream_t stream) {
    const float* x    = (const float*)d_in[0];
    const float* w_in = (const float*)d_in[1];
    const float* b_in = (const float*)d_in[2];
    const float* ln1g = (const float*)d_in[3];
    const float* ln1b = (const float*)d_in[4];
    const float* Wg   = (const float*)d_in[5];
    const float* bg   = (const float*)d_in[6];
    const float* Rg   = (const float*)d_in[7];
    const float* gng  = (const float*)d_in[8];
    const float* gnb  = (const float*)d_in[9];
    const float* ln2g = (const float*)d_in[10];
    const float* ln2b = (const float*)d_in[11];
    const float* W1   = (const float*)d_in[12];
    const float* W2   = (const float*)d_in[13];
    const float* lnfg = (const float*)d_in[14];
    const float* lnfb = (const float*)d_in[15];
    const float* wout = (const float*)d_in[16];
    const float* bout = (const float*)d_in[17];
    float* out = (float*)d_out;

    // ws: h fp32 (134.2 MB) | Wgt bf16 [blk][512][128] | W1t | W2t
    float* h = (float*)d_ws;
    ushort_t* Wgt = (ushort_t*)(h + (size_t)MROWS * 128);
    ushort_t* W1t = Wgt + 2 * 512 * 128;
    ushort_t* W2t = W1t + 2 * 128 * 128;

    k_cvtall<<<(2 * 512 * 128 + 4 * 128 * 128) / 256, 256, 0, stream>>>(
        Wg, W1, W2, Wgt, W1t, W2t);

    // blk 0: embed fused into the scan (reads x, not h)
    k_gslstm<true><<<BB / 16, 512, 0, stream>>>(
        h, x, w_in, b_in, Wgt, bg, Rg, ln1g, ln1b, gng, gnb);
    k_ffn<<<MROWS / 64, 256, 0, stream>>>(h, W1t, W2t, ln2g, ln2b);
    // blk 1
    k_gslstm<false><<<BB / 16, 512, 0, stream>>>(
        h, nullptr, nullptr, nullptr, Wgt + (size_t)512 * 128, bg + 512,
        Rg + (size_t)16384, ln1g + 128, ln1b + 128, gng + 128, gnb + 128);
    k_ffn<<<MROWS / 64, 256, 0, stream>>>(h, W1t + 16384, W2t + 16384,
                                          ln2g + 128, ln2b + 128);
    k_out<<<BB / 4, 256, 0, stream>>>(h, lnfg, lnfb, wout, bout, out);
}

// Round 9
// 457.391 us; speedup vs baseline: 5.1696x; 1.3107x over previous
//
#include <hip/hip_runtime.h>
#include <hip/hip_bf16.h>
#include <cstdint>
#include <cstddef>

#define EPS 1e-5f
#define BB 4096
#define TT 64
#define NBLK 2
#define MROWS (BB * TT)

typedef unsigned short ushort_t;
typedef __attribute__((ext_vector_type(8))) short short8;
typedef __attribute__((ext_vector_type(4))) float floatx4;

__device__ __forceinline__ ushort_t f2b(float f) {
    __hip_bfloat16 h = __float2bfloat16(f);
    return *reinterpret_cast<ushort_t*>(&h);
}
__device__ __forceinline__ float tanh_fast(float z) {
    return 1.f - 2.f / (__expf(2.f * z) + 1.f);
}
// LDS-only barrier, single asm statement (round-5 lesson: separate
// builtin_amdgcn_s_barrier is IntrNoMem and lets LDS ops hoist past the
// waitcnt). Omits vmcnt drain: global buffers are wg-exclusive.
__device__ __forceinline__ void lds_barrier() {
    asm volatile("s_waitcnt lgkmcnt(0)\n\ts_barrier" ::: "memory");
}

// ---------------- all weight converts in one launch ----------------
__global__ __launch_bounds__(256) void k_cvtall(
    const float* __restrict__ Wg, const float* __restrict__ W1,
    const float* __restrict__ W2, ushort_t* __restrict__ Wgt,
    ushort_t* __restrict__ W1t, ushort_t* __restrict__ W2t) {
    int idx = blockIdx.x * 256 + threadIdx.x;
    if (idx < 2 * 512 * 128) {
        int blk = idx >> 16, r = idx & 65535;
        int n = r >> 7, k = r & 127;
        Wgt[idx] = f2b(Wg[(size_t)blk * 65536 + k * 512 + n]);
    } else if (idx < 2 * 512 * 128 + 2 * 128 * 128) {
        int i2 = idx - 2 * 512 * 128;
        int blk = i2 >> 14, r = i2 & 16383;
        int n = r >> 7, k = r & 127;
        W1t[i2] = f2b(W1[(size_t)blk * 16384 + k * 128 + n]);
    } else {
        int i2 = idx - (2 * 512 * 128 + 2 * 128 * 128);
        int blk = i2 >> 14, r = i2 & 16383;
        int n = r >> 7, k = r & 127;
        W2t[i2] = f2b(W2[(size_t)blk * 16384 + k * 128 + n]);
    }
}

// ---------------- fused [embed +] gate-GEMM + sLSTM scan + GroupNorm + residual --------
// ROUND-7 PROVEN SHAPE (deterministic): grid = BB/16 = 256 wgs, 512 thr
// (8 waves -> 2 waves/SIMD). Wg owns 16 batches for all T.
// Wave = (gate, half): gate = wave>>1, N-columns half*64..+64 of that gate.
// LASTONLY (new, store-skip only): blk-1 scan's h rows are dead except t=TT-1.
template <bool EMBED, bool LASTONLY>
__global__ __launch_bounds__(512, 2) void k_gslstm(
    float* __restrict__ h, const float* __restrict__ x,
    const float* __restrict__ w_in, const float* __restrict__ b_in,
    const ushort_t* __restrict__ Wgt, const float* __restrict__ bg,
    const float* __restrict__ Rg,
    const float* __restrict__ ln1g, const float* __restrict__ ln1b,
    const float* __restrict__ gng, const float* __restrict__ gnb) {
    __shared__ ushort_t Afrag[16][136];  // LN1(h_in) bf16, [m][k]
    __shared__ ushort_t Hlds[16][136];   // h_prev bf16, [m][k]
    __shared__ float Xbuf[16][516];      // gate preacts fp32, [b][g*128+d]

    int tid = threadIdx.x;        // 0..511
    int lane = tid & 63;
    int wave = tid >> 6;          // 0..7
    int gate = wave >> 1;
    int half = wave & 1;
    int q = lane >> 4, ml = lane & 15;
    int bo = tid >> 5;            // local batch 0..15 (phase A/C ownership)
    int dl = tid & 31;            // dims dl*4 .. dl*4+3
    int b0 = blockIdx.x * 16;

    // ---- static setup ----
    short8 WB[4][4];  // [k-slice][n-slice] of this wave's 64 columns
#pragma unroll
    for (int ks = 0; ks < 4; ++ks)
#pragma unroll
        for (int s = 0; s < 4; ++s)
            WB[ks][s] = *(const short8*)(Wgt +
                ((size_t)(gate * 128 + half * 64 + s * 16 + ml) * 128 + ks * 32 + q * 8));
    float biasv[4];
#pragma unroll
    for (int s = 0; s < 4; ++s) biasv[s] = bg[gate * 128 + half * 64 + s * 16 + ml];
    // R: heads 2*half+hb (hb<2), n-slice sr<2 -> accumulates into acc[hb*2+sr]
    short8 RB[2][2];
#pragma unroll
    for (int hb = 0; hb < 2; ++hb)
#pragma unroll
        for (int sr = 0; sr < 2; ++sr) {
            ushort_t tmp[8];
#pragma unroll
            for (int jj = 0; jj < 8; ++jj)
                tmp[jj] = f2b(Rg[((size_t)(gate * 4 + 2 * half + hb) * 32 + q * 8 + jj) * 32 +
                               sr * 16 + ml]);
            RB[hb][sr] = *(const short8*)tmp;
        }
    float lng_[4], lnb_[4], gng_[4], gnb_[4];
#pragma unroll
    for (int jj = 0; jj < 4; ++jj) {
        lng_[jj] = ln1g[dl * 4 + jj];
        lnb_[jj] = ln1b[dl * 4 + jj];
        gng_[jj] = gng[dl * 4 + jj];
        gnb_[jj] = gnb[dl * 4 + jj];
    }
    float we0[4], we1[4], we2[4], be[4];
    if (EMBED) {
#pragma unroll
        for (int jj = 0; jj < 4; ++jj) {
            we0[jj] = w_in[0 * 128 + dl * 4 + jj];
            we1[jj] = w_in[1 * 128 + dl * 4 + jj];
            we2[jj] = w_in[2 * 128 + dl * 4 + jj];
            be[jj] = b_in[dl * 4 + jj];
        }
    }
    float cst[4], nst[4], mst[4];
#pragma unroll
    for (int jj = 0; jj < 4; ++jj) { cst[jj] = 0.f; nst[jj] = 0.f; mst[jj] = 0.f; }

    for (int i = tid; i < 16 * 136; i += 512) ((ushort_t*)Hlds)[i] = 0;

    float cur0 = 0.f, cur1 = 0.f, cur2 = 0.f;
    float hin[4];
    if (EMBED) {
        const float* xp = x + (size_t)(b0 + bo) * TT * 3;
        cur0 = xp[0]; cur1 = xp[1]; cur2 = xp[2];
    } else {
        float4 v = *(const float4*)(h + ((size_t)(b0 + bo) * TT) * 128 + dl * 4);
        hin[0] = v.x; hin[1] = v.y; hin[2] = v.z; hin[3] = v.w;
    }
    lds_barrier();

    for (int t = 0; t < TT; ++t) {
        // ---- phase A: h_in + inline LN1 stats + Afrag stage + prefetch t+1 ----
        if (EMBED) {
#pragma unroll
            for (int jj = 0; jj < 4; ++jj)
                hin[jj] = cur0 * we0[jj] + cur1 * we1[jj] + cur2 * we2[jj] + be[jj];
        }
        float s = 0.f, ss = 0.f;
#pragma unroll
        for (int jj = 0; jj < 4; ++jj) { s += hin[jj]; ss += hin[jj] * hin[jj]; }
#pragma unroll
        for (int off = 1; off < 32; off <<= 1) {
            s += __shfl_xor(s, off);
            ss += __shfl_xor(ss, off);
        }
        float mu = s * (1.f / 128.f);
        float rstd = rsqrtf(ss * (1.f / 128.f) - mu * mu + EPS);
        {
            ushort_t ab[4];
#pragma unroll
            for (int jj = 0; jj < 4; ++jj)
                ab[jj] = f2b((hin[jj] - mu) * rstd * lng_[jj] + lnb_[jj]);
            *(uint2*)&Afrag[bo][dl * 4] = *(const uint2*)ab;
        }
        float hin2[4] = {0.f, 0.f, 0.f, 0.f};
        float nx0 = 0.f, nx1 = 0.f, nx2 = 0.f;
        if (t + 1 < TT) {
            if (EMBED) {
                const float* xp = x + ((size_t)(b0 + bo) * TT + t + 1) * 3;
                nx0 = xp[0]; nx1 = xp[1]; nx2 = xp[2];
            } else {
                float4 v = *(const float4*)(h + ((size_t)(b0 + bo) * TT + t + 1) * 128 + dl * 4);
                hin2[0] = v.x; hin2[1] = v.y; hin2[2] = v.z; hin2[3] = v.w;
            }
        }
        lds_barrier();  // b1: Afrag + Hlds(prev C) visible; Xbuf(prev) consumed

        // ---- phase B: MFMA xg + r + bias ----
        short8 af[4], hf[2];
#pragma unroll
        for (int ks = 0; ks < 4; ++ks)
            af[ks] = *(const short8*)&Afrag[ml][ks * 32 + q * 8];
#pragma unroll
        for (int hb = 0; hb < 2; ++hb)
            hf[hb] = *(const short8*)&Hlds[ml][(2 * half + hb) * 32 + q * 8];
        floatx4 acc[4];
#pragma unroll
        for (int s4 = 0; s4 < 4; ++s4) {
            float b = biasv[s4];
            acc[s4] = (floatx4){b, b, b, b};
        }
#pragma unroll
        for (int ks = 0; ks < 4; ++ks)
#pragma unroll
            for (int s4 = 0; s4 < 4; ++s4)
                acc[s4] = __builtin_amdgcn_mfma_f32_16x16x32_bf16(
                    af[ks], WB[ks][s4], acc[s4], 0, 0, 0);
#pragma unroll
        for (int hb = 0; hb < 2; ++hb)
#pragma unroll
            for (int sr = 0; sr < 2; ++sr)
                acc[hb * 2 + sr] = __builtin_amdgcn_mfma_f32_16x16x32_bf16(
                    hf[hb], RB[hb][sr], acc[hb * 2 + sr], 0, 0, 0);
#pragma unroll
        for (int s4 = 0; s4 < 4; ++s4)
#pragma unroll
            for (int r = 0; r < 4; ++r)
                Xbuf[q * 4 + r][gate * 128 + half * 64 + s4 * 16 + ml] = acc[s4][r];
        lds_barrier();  // b2: Xbuf ready

        // ---- phase C: nonlinearities + GN + residual (4 dims/thread) ----
        float it[4], ft[4], zt[4], ot[4];
        {
            float4 a = *(const float4*)&Xbuf[bo][0 * 128 + dl * 4];
            it[0] = a.x; it[1] = a.y; it[2] = a.z; it[3] = a.w;
            float4 f = *(const float4*)&Xbuf[bo][1 * 128 + dl * 4];
            ft[0] = f.x; ft[1] = f.y; ft[2] = f.z; ft[3] = f.w;
            float4 z = *(const float4*)&Xbuf[bo][2 * 128 + dl * 4];
            zt[0] = z.x; zt[1] = z.y; zt[2] = z.z; zt[3] = z.w;
            float4 o = *(const float4*)&Xbuf[bo][3 * 128 + dl * 4];
            ot[0] = o.x; ot[1] = o.y; ot[2] = o.z; ot[3] = o.w;
        }
        float hv[4];
#pragma unroll
        for (int jj = 0; jj < 4; ++jj) {
            float mn = fmaxf(ft[jj] + mst[jj], it[jj]);
            float iv = __expf(it[jj] - mn);
            float fv = __expf(ft[jj] + mst[jj] - mn);
            float cn = fv * cst[jj] + iv * tanh_fast(zt[jj]);
            float nn = fv * nst[jj] + iv;
            hv[jj] = cn / (nn * (1.f + __expf(-ot[jj])));
            cst[jj] = cn; nst[jj] = nn; mst[jj] = mn;
        }
        // GroupNorm over head (32 dims): 4 local + shfl over dl bits 0-2
        float s2 = 0.f, q2 = 0.f;
#pragma unroll
        for (int jj = 0; jj < 4; ++jj) { s2 += hv[jj]; q2 += hv[jj] * hv[jj]; }
        s2 += __shfl_xor(s2, 1); q2 += __shfl_xor(q2, 1);
        s2 += __shfl_xor(s2, 2); q2 += __shfl_xor(q2, 2);
        s2 += __shfl_xor(s2, 4); q2 += __shfl_xor(q2, 4);
        float mu2 = s2 * (1.f / 32.f);
        float rstd2 = rsqrtf(q2 * (1.f / 32.f) - mu2 * mu2 + EPS);
        {
            if (!LASTONLY || t == TT - 1) {
                float o[4];
#pragma unroll
                for (int jj = 0; jj < 4; ++jj)
                    o[jj] = hin[jj] + (hv[jj] - mu2) * rstd2 * gng_[jj] + gnb_[jj];
                float* po = h + ((size_t)(b0 + bo) * TT + t) * 128 + dl * 4;
                *(float4*)po = make_float4(o[0], o[1], o[2], o[3]);
            }
            ushort_t hb16[4];
#pragma unroll
            for (int jj = 0; jj < 4; ++jj) hb16[jj] = f2b(hv[jj]);
            *(uint2*)&Hlds[bo][dl * 4] = *(const uint2*)hb16;
        }
        if (EMBED) { cur0 = nx0; cur1 = nx1; cur2 = nx2; }
        else {
#pragma unroll
            for (int jj = 0; jj < 4; ++jj) hin[jj] = hin2[jj];
        }
        // no barrier: next phase A writes only Afrag (disjoint); b1 orders
        // Hlds writes + Xbuf reads before next phase B.
    }
}

// ---------------- fused FFN: h += gelu(LN2(h) @ W1) @ W2, stats inline ----------------
// M=64 tiles, 34.8 KB LDS -> 3 wgs/CU. LAST: rows map to (batch)*TT + TT-1
// (blk-1: only t=TT-1 rows are live). Per-row LN + row-independent MFMA =>
// bit-identical per-row results vs the full variant.
template <bool LAST>
__global__ __launch_bounds__(256, 3) void k_ffn(
    float* __restrict__ h, const ushort_t* __restrict__ W1t,
    const ushort_t* __restrict__ W2t,
    const float* __restrict__ lng, const float* __restrict__ lnb) {
    __shared__ ushort_t As[64][136];
    __shared__ ushort_t T1[64][136];
    int tid = threadIdx.x;
    int lane = tid & 63, wave = tid >> 6;
    int q = lane >> 4, ml = lane & 15;
    int wn = wave * 32;  // wave's 32-column slice
    size_t row0 = (size_t)blockIdx.x * 64;

    // hoist W1 fragments (latency hidden under stats)
    short8 W1B[2][4];
#pragma unroll
    for (int jn = 0; jn < 2; ++jn)
#pragma unroll
        for (int ks = 0; ks < 4; ++ks)
            W1B[jn][ks] = *(const short8*)(W1t +
                ((size_t)(wn + jn * 16 + ml) * 128 + ks * 32 + q * 8));

    // inline LN2 stats: 4 threads per row, 32 dims each
    int r = tid >> 2, qd = tid & 3;
    size_t grow = LAST ? ((row0 + r) * TT + (TT - 1)) : (row0 + r);
    const float* hrow = h + grow * 128 + qd * 32;
    float s = 0.f, ss = 0.f;
#pragma unroll
    for (int k = 0; k < 8; ++k) {
        float4 v = ((const float4*)hrow)[k];
        s += v.x + v.y + v.z + v.w;
        ss += v.x * v.x + v.y * v.y + v.z * v.z + v.w * v.w;
    }
    s += __shfl_xor(s, 1); ss += __shfl_xor(ss, 1);
    s += __shfl_xor(s, 2); ss += __shfl_xor(ss, 2);
    float mu = s * (1.f / 128.f);
    float rstd = rsqrtf(ss * (1.f / 128.f) - mu * mu + EPS);
#pragma unroll
    for (int kk = 0; kk < 4; ++kk) {
        float4 a = ((const float4*)hrow)[2 * kk];
        float4 b = ((const float4*)hrow)[2 * kk + 1];
        int c0 = qd * 32 + kk * 8;
        float4 g0 = *(const float4*)(lng + c0);
        float4 g1 = *(const float4*)(lng + c0 + 4);
        float4 b0 = *(const float4*)(lnb + c0);
        float4 b1 = *(const float4*)(lnb + c0 + 4);
        ushort_t p[8];
        p[0] = f2b((a.x - mu) * rstd * g0.x + b0.x);
        p[1] = f2b((a.y - mu) * rstd * g0.y + b0.y);
        p[2] = f2b((a.z - mu) * rstd * g0.z + b0.z);
        p[3] = f2b((a.w - mu) * rstd * g0.w + b0.w);
        p[4] = f2b((b.x - mu) * rstd * g1.x + b1.x);
        p[5] = f2b((b.y - mu) * rstd * g1.y + b1.y);
        p[6] = f2b((b.z - mu) * rstd * g1.z + b1.z);
        p[7] = f2b((b.w - mu) * rstd * g1.w + b1.w);
        *(short8*)&As[r][c0] = *(const short8*)p;
    }
    lds_barrier();

    // MFMA1: t1 = gelu(As @ W1)
    floatx4 acc[4][2];
#pragma unroll
    for (int i = 0; i < 4; ++i)
#pragma unroll
        for (int j = 0; j < 2; ++j) acc[i][j] = (floatx4)0.f;
#pragma unroll
    for (int ks = 0; ks < 4; ++ks) {
        short8 af[4];
#pragma unroll
        for (int im = 0; im < 4; ++im)
            af[im] = *(const short8*)&As[im * 16 + ml][ks * 32 + q * 8];
#pragma unroll
        for (int im = 0; im < 4; ++im)
#pragma unroll
            for (int jn = 0; jn < 2; ++jn)
                acc[im][jn] = __builtin_amdgcn_mfma_f32_16x16x32_bf16(
                    af[im], W1B[jn][ks], acc[im][jn], 0, 0, 0);
    }
#pragma unroll
    for (int im = 0; im < 4; ++im)
#pragma unroll
        for (int jn = 0; jn < 2; ++jn)
#pragma unroll
            for (int rr = 0; rr < 4; ++rr) {
                float v = acc[im][jn][rr];
                float u = 0.7978845608028654f * (v + 0.044715f * v * v * v);
                float gv = 0.5f * v * (1.f + tanh_fast(u));
                T1[im * 16 + q * 4 + rr][wn + jn * 16 + ml] = f2b(gv);
            }
    // prefetch W2 fragments before the barrier
    short8 W2B[2][4];
#pragma unroll
    for (int jn = 0; jn < 2; ++jn)
#pragma unroll
        for (int ks = 0; ks < 4; ++ks)
            W2B[jn][ks] = *(const short8*)(W2t +
                ((size_t)(wn + jn * 16 + ml) * 128 + ks * 32 + q * 8));
    lds_barrier();

    // MFMA2: h += T1 @ W2
#pragma unroll
    for (int i = 0; i < 4; ++i)
#pragma unroll
        for (int j = 0; j < 2; ++j) acc[i][j] = (floatx4)0.f;
#pragma unroll
    for (int ks = 0; ks < 4; ++ks) {
        short8 af[4];
#pragma unroll
        for (int im = 0; im < 4; ++im)
            af[im] = *(const short8*)&T1[im * 16 + ml][ks * 32 + q * 8];
#pragma unroll
        for (int im = 0; im < 4; ++im)
#pragma unroll
            for (int jn = 0; jn < 2; ++jn)
                acc[im][jn] = __builtin_amdgcn_mfma_f32_16x16x32_bf16(
                    af[im], W2B[jn][ks], acc[im][jn], 0, 0, 0);
    }
#pragma unroll
    for (int im = 0; im < 4; ++im)
#pragma unroll
        for (int jn = 0; jn < 2; ++jn)
#pragma unroll
            for (int rr = 0; rr < 4; ++rr) {
                int rloc = im * 16 + q * 4 + rr;
                size_t rw = LAST ? ((row0 + rloc) * TT + (TT - 1)) : (row0 + rloc);
                int cc = wn + jn * 16 + ml;
                h[rw * 128 + cc] += acc[im][jn][rr];
            }
}

// ---------------- final LN (t=T-1 only) + matvec ----------------
__global__ __launch_bounds__(256) void k_out(const float* __restrict__ h,
                                             const float* __restrict__ lnfg,
                                             const float* __restrict__ lnfb,
                                             const float* __restrict__ w_out,
                                             const float* __restrict__ b_out,
                                             float* __restrict__ out) {
    int b = blockIdx.x * 4 + (threadIdx.x >> 6);
    int l = threadIdx.x & 63;
    const float* hr = h + ((size_t)b * TT + (TT - 1)) * 128;
    float2 v = *(const float2*)(hr + l * 2);
    float s = v.x + v.y, ss = v.x * v.x + v.y * v.y;
#pragma unroll
    for (int off = 1; off < 64; off <<= 1) {
        s += __shfl_xor(s, off);
        ss += __shfl_xor(ss, off);
    }
    float mu_ = s * (1.f / 128.f);
    float rstd = rsqrtf(ss * (1.f / 128.f) - mu_ * mu_ + EPS);
    float2 g = *(const float2*)(lnfg + l * 2);
    float2 bb = *(const float2*)(lnfb + l * 2);
    float2 w = *(const float2*)(w_out + l * 2);
    float dot = ((v.x - mu_) * rstd * g.x + bb.x) * w.x +
                ((v.y - mu_) * rstd * g.y + bb.y) * w.y;
#pragma unroll
    for (int off = 1; off < 64; off <<= 1) dot += __shfl_xor(dot, off);
    if (l == 0) out[b] = dot + b_out[0];
}

extern "C" void kernel_launch(void* const* d_in, const int* in_sizes, int n_in,
                              void* d_out, int out_size, void* d_ws, size_t ws_size,
                              hipStream_t stream) {
    const float* x    = (const float*)d_in[0];
    const float* w_in = (const float*)d_in[1];
    const float* b_in = (const float*)d_in[2];
    const float* ln1g = (const float*)d_in[3];
    const float* ln1b = (const float*)d_in[4];
    const float* Wg   = (const float*)d_in[5];
    const float* bg   = (const float*)d_in[6];
    const float* Rg   = (const float*)d_in[7];
    const float* gng  = (const float*)d_in[8];
    const float* gnb  = (const float*)d_in[9];
    const float* ln2g = (const float*)d_in[10];
    const float* ln2b = (const float*)d_in[11];
    const float* W1   = (const float*)d_in[12];
    const float* W2   = (const float*)d_in[13];
    const float* lnfg = (const float*)d_in[14];
    const float* lnfb = (const float*)d_in[15];
    const float* wout = (const float*)d_in[16];
    const float* bout = (const float*)d_in[17];
    float* out = (float*)d_out;

    // ws: h fp32 (134.2 MB) | Wgt bf16 [blk][512][128] | W1t | W2t
    float* h = (float*)d_ws;
    ushort_t* Wgt = (ushort_t*)(h + (size_t)MROWS * 128);
    ushort_t* W1t = Wgt + 2 * 512 * 128;
    ushort_t* W2t = W1t + 2 * 128 * 128;

    k_cvtall<<<(2 * 512 * 128 + 4 * 128 * 128) / 256, 256, 0, stream>>>(
        Wg, W1, W2, Wgt, W1t, W2t);

    // blk 0: embed fused into the scan (reads x, not h); full h written
    k_gslstm<true, false><<<BB / 16, 512, 0, stream>>>(
        h, x, w_in, b_in, Wgt, bg, Rg, ln1g, ln1b, gng, gnb);
    k_ffn<false><<<MROWS / 64, 256, 0, stream>>>(h, W1t, W2t, ln2g, ln2b);
    // blk 1: h writes dead except t=T-1 (only FFN1@t=T-1 -> k_out read them)
    k_gslstm<false, true><<<BB / 16, 512, 0, stream>>>(
        h, nullptr, nullptr, nullptr, Wgt + (size_t)512 * 128, bg + 512,
        Rg + (size_t)16384, ln1g + 128, ln1b + 128, gng + 128, gnb + 128);
    k_ffn<true><<<BB / 64, 256, 0, stream>>>(h, W1t + 16384, W2t + 16384,
                                             ln2g + 128, ln2b + 128);
    k_out<<<BB / 4, 256, 0, stream>>>(h, lnfg, lnfb, wout, bout, out);
}